// Round 1
// baseline (718.846 us; speedup 1.0000x reference)
//
#include <hip/hip_runtime.h>
#include <hip/hip_bf16.h>

#define HW 9216
#define NPIX 18432

// ---------------- transpose NCHW -> NHWC (channels-last) ----------------
__global__ void transpose_cl_k(const float* __restrict__ past,
                               const float* __restrict__ curr,
                               float* __restrict__ past_cl,
                               float* __restrict__ curr_cl) {
    __shared__ float tile[32][33];
    int t = blockIdx.z & 1, b = blockIdx.z >> 1;
    const float* src = t ? curr : past;
    float* dst = t ? curr_cl : past_cl;
    int p0 = blockIdx.x * 32, c0 = blockIdx.y * 32;
    for (int k = threadIdx.y; k < 32; k += 8)
        tile[k][threadIdx.x] = src[(size_t)(b * 64 + c0 + k) * HW + p0 + threadIdx.x];
    __syncthreads();
    for (int k = threadIdx.y; k < 32; k += 8)
        dst[(size_t)(b * HW + p0 + k) * 64 + c0 + threadIdx.x] = tile[threadIdx.x][k];
}

// ---------------- shift + grouped 3x3 smooth conv (groups=8) ----------------
// shifted[g][y][x] = past[g][y-sy, x-sx] (0 outside); conv zero-pads at [0,96) too.
__global__ void smooth_k(const float* __restrict__ past_cl,
                         const float* __restrict__ w_smooth,
                         const float* __restrict__ b_smooth,
                         float* __restrict__ smooth_cl) {
    int tid = threadIdx.x;
    int o = tid & 63;
    int p = blockIdx.x * 4 + (tid >> 6);
    int b = p / HW, rem = p - b * HW;
    int y = rem / 96, x = rem - y * 96;
    int g = o >> 3;
    int gi = g < 4 ? g : g + 1;          // skip (0,0) in 3x3 row-major
    int sy = gi / 3 - 1, sx = gi % 3 - 1;
    float acc = b_smooth[o];
    const float* base = past_cl + (size_t)b * HW * 64;
    for (int ky = 0; ky < 3; ++ky) {
        int yy = y + ky - 1;
        if ((unsigned)yy >= 96u) continue;   // conv zero-pad
        int ys = yy - sy;
        if ((unsigned)ys >= 96u) continue;   // shifted-in zeros
        for (int kx = 0; kx < 3; ++kx) {
            int xx = x + kx - 1;
            if ((unsigned)xx >= 96u) continue;
            int xs = xx - sx;
            if ((unsigned)xs >= 96u) continue;
            const float* ip = base + (size_t)(ys * 96 + xs) * 64 + g * 8;
            const float* wp = w_smooth + o * 72 + ky * 3 + kx;
            #pragma unroll
            for (int cig = 0; cig < 8; ++cig)
                acc += wp[cig * 9] * ip[cig];
        }
    }
    smooth_cl[(size_t)p * 64 + o] = acc;
}

// ---------------- 1x1 reduce: concat(past, smooth) (128) -> 64 ----------------
__global__ void reduce_k(const float* __restrict__ past_cl,
                         const float* __restrict__ smooth_cl,
                         const float* __restrict__ w_reduce,
                         const float* __restrict__ b_reduce,
                         float* __restrict__ past2_cl) {
    int tid = threadIdx.x;
    int o = tid & 63;
    int p = blockIdx.x * 4 + (tid >> 6);
    const float* wp = w_reduce + o * 128;
    const float* a = past_cl + (size_t)p * 64;
    const float* s = smooth_cl + (size_t)p * 64;
    float acc = b_reduce[o];
    #pragma unroll 8
    for (int c = 0; c < 64; ++c) acc += wp[c] * a[c];
    #pragma unroll 8
    for (int c = 0; c < 64; ++c) acc += wp[64 + c] * s[c];
    past2_cl[(size_t)p * 64 + o] = acc;
}

// ---------------- both V 1x1 convs from past2 ----------------
__global__ void vv_k(const float* __restrict__ past2_cl,
                     const float* __restrict__ w_v0, const float* __restrict__ b_v0,
                     const float* __restrict__ w_v1, const float* __restrict__ b_v1,
                     float* __restrict__ v0_cl, float* __restrict__ v1_cl) {
    int tid = threadIdx.x;
    int o = tid & 63;
    int p = blockIdx.x * 4 + (tid >> 6);
    const float* a = past2_cl + (size_t)p * 64;
    float acc0 = b_v0[o], acc1 = b_v1[o];
    const float* w0 = w_v0 + o * 64;
    const float* w1 = w_v1 + o * 64;
    #pragma unroll 8
    for (int c = 0; c < 64; ++c) { float v = a[c]; acc0 += w0[c] * v; acc1 += w1[c] * v; }
    v0_cl[(size_t)p * 64 + o] = acc0;
    v1_cl[(size_t)p * 64 + o] = acc1;
}

// ---------------- neighborhood attention (clipped window) ----------------
template <int KS>
__global__ void natten_k(const float* __restrict__ q_cl,
                         const float* __restrict__ k_cl,
                         const float* __restrict__ v_cl,
                         const float* __restrict__ rpb,
                         float* __restrict__ out_cl) {
    constexpr int KK = KS * KS, R = KS / 2, RW = 2 * KS - 1;
    int tid = threadIdx.x;
    int l = tid & 63, wid = tid >> 6;
    int p = blockIdx.x * 4 + wid;
    int b = p / HW, rem = p - b * HW;
    int y = rem / 96, x = rem - y * 96;
    int y0 = y - R; y0 = y0 < 0 ? 0 : (y0 > 96 - KS ? 96 - KS : y0);
    int x0 = x - R; x0 = x0 < 0 ? 0 : (x0 > 96 - KS ? 96 - KS : x0);
    __shared__ float attn_s[4][64];

    // phase 1: lane = neighbor; dot(q, k_n) + rpb
    float sc = -1e30f;
    if (l < KK) {
        int i = l / KS, j = l - i * KS;
        int ky = y0 + i, kx = x0 + j;
        const float* kp = k_cl + ((size_t)b * HW + ky * 96 + kx) * 64;
        const float* qp = q_cl + (size_t)p * 64;
        float s = 0.f;
        #pragma unroll 8
        for (int c = 0; c < 64; ++c) s += qp[c] * kp[c];
        sc = s + rpb[(ky - y + KS - 1) * RW + (kx - x + KS - 1)];
    }
    // wave softmax over KK lanes
    float m = sc;
    for (int off = 32; off; off >>= 1) m = fmaxf(m, __shfl_xor(m, off));
    float e = (l < KK) ? __expf(sc - m) : 0.f;
    float sum = e;
    for (int off = 32; off; off >>= 1) sum += __shfl_xor(sum, off);
    attn_s[wid][l] = e / sum;
    __syncthreads();

    // phase 2: lane = channel
    float acc = 0.f;
    const float* vb = v_cl + (size_t)b * HW * 64;
    for (int n = 0; n < KK; ++n) {
        int i = n / KS, j = n - i * KS;
        acc += attn_s[wid][n] * vb[((y0 + i) * 96 + x0 + j) * 64 + l];
    }
    out_cl[(size_t)p * 64 + l] = acc;
}

// ---------------- fuse conv 3x3: concat(past,out0,out1) (192) -> 64, NCHW out ----------------
__global__ void fuse_k(const float* __restrict__ past_cl,
                       const float* __restrict__ out0_cl,
                       const float* __restrict__ out1_cl,
                       const float* __restrict__ w_fuse,
                       const float* __restrict__ b_fuse,
                       float* __restrict__ out) {
    __shared__ float lds[3 * 18 * 192];  // 41.5 KB: rows y-1..y+1, cols x0-1..x0+16, 192 ch
    int strip = blockIdx.x;
    int x0 = (strip % 6) * 16;
    int row = strip / 6;
    int b = row / 96, y = row - b * 96;

    const float* srcs[3] = { past_cl + (size_t)b * HW * 64,
                             out0_cl + (size_t)b * HW * 64,
                             out1_cl + (size_t)b * HW * 64 };
    for (int e = threadIdx.x; e < 3 * 18 * 192; e += 256) {
        int c = e % 192;
        int col = (e / 192) % 18;
        int r = e / (192 * 18);
        int yy = y - 1 + r, xx = x0 - 1 + col;
        float v = 0.f;
        if ((unsigned)yy < 96u && (unsigned)xx < 96u)
            v = srcs[c >> 6][(size_t)(yy * 96 + xx) * 64 + (c & 63)];
        lds[e] = v;
    }
    __syncthreads();

    int o = threadIdx.x & 63, w = threadIdx.x >> 6;  // wave w owns pixels x0+4w..x0+4w+3
    float acc0 = b_fuse[o], acc1 = acc0, acc2 = acc0, acc3 = acc0;
    const float* wf = w_fuse + (size_t)o * 1728;
    int colbase = w * 4;
    for (int c = 0; c < 192; ++c) {
        const float* wr = wf + c * 9;
        #pragma unroll
        for (int ky = 0; ky < 3; ++ky) {
            float w0 = wr[ky * 3 + 0], w1 = wr[ky * 3 + 1], w2 = wr[ky * 3 + 2];
            const float* lr = lds + (ky * 18 + colbase) * 192 + c;
            float i0 = lr[0 * 192], i1 = lr[1 * 192], i2 = lr[2 * 192];
            float i3 = lr[3 * 192], i4 = lr[4 * 192], i5 = lr[5 * 192];
            acc0 += w0 * i0 + w1 * i1 + w2 * i2;
            acc1 += w0 * i1 + w1 * i2 + w2 * i3;
            acc2 += w0 * i2 + w1 * i3 + w2 * i4;
            acc3 += w0 * i3 + w1 * i4 + w2 * i5;
        }
    }
    float* op = out + ((size_t)(b * 64 + o) * 96 + y) * 96 + x0 + w * 4;
    op[0] = acc0; op[1] = acc1; op[2] = acc2; op[3] = acc3;
}

extern "C" void kernel_launch(void* const* d_in, const int* in_sizes, int n_in,
                              void* d_out, int out_size, void* d_ws, size_t ws_size,
                              hipStream_t stream) {
    const float* past     = (const float*)d_in[0];
    const float* curr     = (const float*)d_in[1];
    const float* w_smooth = (const float*)d_in[2];
    const float* b_smooth = (const float*)d_in[3];
    const float* w_reduce = (const float*)d_in[4];
    const float* b_reduce = (const float*)d_in[5];
    const float* w_v0     = (const float*)d_in[6];
    const float* b_v0     = (const float*)d_in[7];
    const float* w_v1     = (const float*)d_in[8];
    const float* b_v1     = (const float*)d_in[9];
    const float* rpb0     = (const float*)d_in[10];
    const float* rpb1     = (const float*)d_in[11];
    const float* w_fuse   = (const float*)d_in[12];
    const float* b_fuse   = (const float*)d_in[13];
    float* out = (float*)d_out;
    float* ws  = (float*)d_ws;

    const size_t NF = (size_t)NPIX * 64;
    float* past_cl   = ws;
    float* curr_cl   = ws + NF;
    float* smooth_cl = ws + 2 * NF;
    float* past2_cl  = ws + 3 * NF;
    float* v0_cl     = ws + 4 * NF;
    float* v1_cl     = ws + 5 * NF;
    float* out0_cl   = ws + 6 * NF;
    float* out1_cl   = ws + 7 * NF;

    dim3 tb(32, 8, 1), tg(HW / 32, 2, 4);
    transpose_cl_k<<<tg, tb, 0, stream>>>(past, curr, past_cl, curr_cl);
    smooth_k<<<NPIX / 4, 256, 0, stream>>>(past_cl, w_smooth, b_smooth, smooth_cl);
    reduce_k<<<NPIX / 4, 256, 0, stream>>>(past_cl, smooth_cl, w_reduce, b_reduce, past2_cl);
    vv_k<<<NPIX / 4, 256, 0, stream>>>(past2_cl, w_v0, b_v0, w_v1, b_v1, v0_cl, v1_cl);
    natten_k<3><<<NPIX / 4, 256, 0, stream>>>(curr_cl, past2_cl, v0_cl, rpb0, out0_cl);
    natten_k<7><<<NPIX / 4, 256, 0, stream>>>(curr_cl, past2_cl, v1_cl, rpb1, out1_cl);
    fuse_k<<<1152, 256, 0, stream>>>(past_cl, out0_cl, out1_cl, w_fuse, b_fuse, out);
}

// Round 2
// 322.726 us; speedup vs baseline: 2.2274x; 2.2274x over previous
//
#include <hip/hip_runtime.h>
#include <hip/hip_bf16.h>

#define HW 9216
#define NPIX 18432

typedef __attribute__((ext_vector_type(8))) short short8v;
typedef __attribute__((ext_vector_type(4))) float f32x4;

// ---------------- weight prep: bf16 + fuse-weight transpose to [o][tap][c] ----------------
__global__ void prep_k(const float* __restrict__ w_fuse, const float* __restrict__ w_reduce,
                       const float* __restrict__ w_v0, const float* __restrict__ w_v1,
                       __hip_bfloat16* __restrict__ wt_fuse, __hip_bfloat16* __restrict__ wr_b,
                       __hip_bfloat16* __restrict__ wv0_b, __hip_bfloat16* __restrict__ wv1_b) {
    int i = blockIdx.x * 256 + threadIdx.x;
    if (i < 110592) {
        int o = i / 1728, r = i - o * 1728, tap = r / 192, c = r - tap * 192;
        wt_fuse[i] = __float2bfloat16(w_fuse[o * 1728 + c * 9 + tap]);
    }
    if (i < 8192) wr_b[i] = __float2bfloat16(w_reduce[i]);
    if (i < 4096) { wv0_b[i] = __float2bfloat16(w_v0[i]); wv1_b[i] = __float2bfloat16(w_v1[i]); }
}

// ---------------- transpose NCHW -> NHWC; past also -> featp(bf16, padded) & ps_b ----------------
__global__ void transpose_cl_k(const float* __restrict__ past,
                               const float* __restrict__ curr,
                               float* __restrict__ past_cl,
                               float* __restrict__ curr_cl,
                               __hip_bfloat16* __restrict__ featp,
                               __hip_bfloat16* __restrict__ ps_b) {
    __shared__ float tile[32][33];
    int t = blockIdx.z & 1, b = blockIdx.z >> 1;
    const float* src = t ? curr : past;
    float* dst = t ? curr_cl : past_cl;
    int p0 = blockIdx.x * 32, c0 = blockIdx.y * 32;
    for (int k = threadIdx.y; k < 32; k += 8)
        tile[k][threadIdx.x] = src[(size_t)(b * 64 + c0 + k) * HW + p0 + threadIdx.x];
    __syncthreads();
    for (int k = threadIdx.y; k < 32; k += 8) {
        float v = tile[threadIdx.x][k];
        int pp = p0 + k;
        dst[((size_t)b * HW + pp) * 64 + c0 + threadIdx.x] = v;
        if (!t) {
            __hip_bfloat16 hv = __float2bfloat16(v);
            int y = pp / 96, x = pp - (pp / 96) * 96;
            featp[(((size_t)b * 98 + y + 1) * 98 + x + 1) * 192 + c0 + threadIdx.x] = hv;
            ps_b[((size_t)b * HW + pp) * 128 + c0 + threadIdx.x] = hv;
        }
    }
}

// ---------------- shift + grouped 3x3 smooth conv -> ps_b[:,64:128] (bf16) ----------------
__global__ void smooth_k(const float* __restrict__ past_cl,
                         const float* __restrict__ w_smooth,
                         const float* __restrict__ b_smooth,
                         __hip_bfloat16* __restrict__ ps_b) {
    int tid = threadIdx.x;
    int o = tid & 63;
    int p = blockIdx.x * 4 + (tid >> 6);
    int b = p / HW, rem = p - b * HW;
    int y = rem / 96, x = rem - y * 96;
    int g = o >> 3;
    int gi = g < 4 ? g : g + 1;          // skip (0,0) in 3x3 row-major
    int sy = gi / 3 - 1, sx = gi % 3 - 1;
    float acc = b_smooth[o];
    const float* base = past_cl + (size_t)b * HW * 64;
    for (int ky = 0; ky < 3; ++ky) {
        int yy = y + ky - 1;
        if ((unsigned)yy >= 96u) continue;   // conv zero-pad
        int ys = yy - sy;
        if ((unsigned)ys >= 96u) continue;   // shifted-in zeros
        for (int kx = 0; kx < 3; ++kx) {
            int xx = x + kx - 1;
            if ((unsigned)xx >= 96u) continue;
            int xs = xx - sx;
            if ((unsigned)xs >= 96u) continue;
            const float* ip = base + (size_t)(ys * 96 + xs) * 64 + g * 8;
            const float* wp = w_smooth + o * 72 + ky * 3 + kx;
            #pragma unroll
            for (int cig = 0; cig < 8; ++cig)
                acc += wp[cig * 9] * ip[cig];
        }
    }
    ps_b[(size_t)p * 128 + 64 + o] = __float2bfloat16(acc);
}

// ---------------- MFMA 1x1 reduce: ps_b [p][128] x wr_b [64][128]^T -> past2 ----------------
__global__ void reduce_mfma_k(const __hip_bfloat16* __restrict__ ps_b,
                              const __hip_bfloat16* __restrict__ wr_b,
                              const float* __restrict__ b_reduce,
                              float* __restrict__ past2_cl,
                              __hip_bfloat16* __restrict__ past2_b) {
    int p0 = blockIdx.x * 32;
    int tid = threadIdx.x, l = tid & 63, w = tid >> 6;
    int mtile = w >> 1, nbase = (w & 1) * 32;
    int lm = l & 15, g = l >> 4;
    f32x4 acc0 = {0, 0, 0, 0}, acc1 = {0, 0, 0, 0};
    const __hip_bfloat16* ap  = ps_b + (size_t)(p0 + mtile * 16 + lm) * 128 + g * 8;
    const __hip_bfloat16* b0p = wr_b + (size_t)(nbase + lm) * 128 + g * 8;
    const __hip_bfloat16* b1p = b0p + 16 * 128;
    #pragma unroll
    for (int c0 = 0; c0 < 128; c0 += 32) {
        short8v a  = *reinterpret_cast<const short8v*>(ap + c0);
        short8v b0 = *reinterpret_cast<const short8v*>(b0p + c0);
        short8v b1 = *reinterpret_cast<const short8v*>(b1p + c0);
        acc0 = __builtin_amdgcn_mfma_f32_16x16x32_bf16(a, b0, acc0, 0, 0, 0);
        acc1 = __builtin_amdgcn_mfma_f32_16x16x32_bf16(a, b1, acc1, 0, 0, 0);
    }
    int o0 = nbase + lm, o1 = o0 + 16;
    float bias0 = b_reduce[o0], bias1 = b_reduce[o1];
    #pragma unroll
    for (int r = 0; r < 4; ++r) {
        int p = p0 + mtile * 16 + g * 4 + r;
        float v0 = acc0[r] + bias0, v1 = acc1[r] + bias1;
        past2_cl[(size_t)p * 64 + o0] = v0;
        past2_cl[(size_t)p * 64 + o1] = v1;
        past2_b[(size_t)p * 64 + o0] = __float2bfloat16(v0);
        past2_b[(size_t)p * 64 + o1] = __float2bfloat16(v1);
    }
}

// ---------------- MFMA both V 1x1 convs ----------------
__global__ void vv_mfma_k(const __hip_bfloat16* __restrict__ past2_b,
                          const __hip_bfloat16* __restrict__ wv0_b,
                          const __hip_bfloat16* __restrict__ wv1_b,
                          const float* __restrict__ b_v0, const float* __restrict__ b_v1,
                          float* __restrict__ v0_cl, float* __restrict__ v1_cl) {
    int p0 = blockIdx.x * 32;
    int tid = threadIdx.x, l = tid & 63, w = tid >> 6;
    int mtile = w >> 1, nbase = (w & 1) * 32;
    int lm = l & 15, g = l >> 4;
    f32x4 acc00 = {0,0,0,0}, acc01 = {0,0,0,0}, acc10 = {0,0,0,0}, acc11 = {0,0,0,0};
    const __hip_bfloat16* ap = past2_b + (size_t)(p0 + mtile * 16 + lm) * 64 + g * 8;
    size_t bo = (size_t)(nbase + lm) * 64 + g * 8;
    #pragma unroll
    for (int c0 = 0; c0 < 64; c0 += 32) {
        short8v a   = *reinterpret_cast<const short8v*>(ap + c0);
        short8v b00 = *reinterpret_cast<const short8v*>(wv0_b + bo + c0);
        short8v b01 = *reinterpret_cast<const short8v*>(wv0_b + bo + 16 * 64 + c0);
        short8v b10 = *reinterpret_cast<const short8v*>(wv1_b + bo + c0);
        short8v b11 = *reinterpret_cast<const short8v*>(wv1_b + bo + 16 * 64 + c0);
        acc00 = __builtin_amdgcn_mfma_f32_16x16x32_bf16(a, b00, acc00, 0, 0, 0);
        acc01 = __builtin_amdgcn_mfma_f32_16x16x32_bf16(a, b01, acc01, 0, 0, 0);
        acc10 = __builtin_amdgcn_mfma_f32_16x16x32_bf16(a, b10, acc10, 0, 0, 0);
        acc11 = __builtin_amdgcn_mfma_f32_16x16x32_bf16(a, b11, acc11, 0, 0, 0);
    }
    int o0 = nbase + lm, o1 = o0 + 16;
    float bi00 = b_v0[o0], bi01 = b_v0[o1], bi10 = b_v1[o0], bi11 = b_v1[o1];
    #pragma unroll
    for (int r = 0; r < 4; ++r) {
        int p = p0 + mtile * 16 + g * 4 + r;
        v0_cl[(size_t)p * 64 + o0] = acc00[r] + bi00;
        v0_cl[(size_t)p * 64 + o1] = acc01[r] + bi01;
        v1_cl[(size_t)p * 64 + o0] = acc10[r] + bi10;
        v1_cl[(size_t)p * 64 + o1] = acc11[r] + bi11;
    }
}

// ---------------- neighborhood attention (clipped window), out -> featp bf16 ----------------
template <int KS>
__global__ void natten_k(const float* __restrict__ q_cl,
                         const float* __restrict__ k_cl,
                         const float* __restrict__ v_cl,
                         const float* __restrict__ rpb,
                         __hip_bfloat16* __restrict__ featp, int coff) {
    constexpr int KK = KS * KS, R = KS / 2, RW = 2 * KS - 1;
    int tid = threadIdx.x;
    int l = tid & 63, wid = tid >> 6;
    int p = blockIdx.x * 4 + wid;
    int b = p / HW, rem = p - b * HW;
    int y = rem / 96, x = rem - y * 96;
    int y0 = y - R; y0 = y0 < 0 ? 0 : (y0 > 96 - KS ? 96 - KS : y0);
    int x0 = x - R; x0 = x0 < 0 ? 0 : (x0 > 96 - KS ? 96 - KS : x0);
    __shared__ float attn_s[4][64];

    // phase 1: lane = neighbor; dot(q, k_n) + rpb (float4-vectorized)
    float sc = -1e30f;
    if (l < KK) {
        int i = l / KS, j = l - i * KS;
        int ky = y0 + i, kx = x0 + j;
        const float4* kp = (const float4*)(k_cl + ((size_t)b * HW + ky * 96 + kx) * 64);
        const float4* qp = (const float4*)(q_cl + (size_t)p * 64);
        float s = 0.f;
        #pragma unroll 4
        for (int c = 0; c < 16; ++c) {
            float4 qv = qp[c], kv = kp[c];
            s += qv.x * kv.x + qv.y * kv.y + qv.z * kv.z + qv.w * kv.w;
        }
        sc = s + rpb[(ky - y + KS - 1) * RW + (kx - x + KS - 1)];
    }
    // wave softmax over KK lanes
    float m = sc;
    for (int off = 32; off; off >>= 1) m = fmaxf(m, __shfl_xor(m, off));
    float e = (l < KK) ? __expf(sc - m) : 0.f;
    float sum = e;
    for (int off = 32; off; off >>= 1) sum += __shfl_xor(sum, off);
    attn_s[wid][l] = e / sum;
    __syncthreads();

    // phase 2: lane = channel
    float acc = 0.f;
    const float* vb = v_cl + (size_t)b * HW * 64;
    for (int n = 0; n < KK; ++n) {
        int i = n / KS, j = n - i * KS;
        acc += attn_s[wid][n] * vb[((y0 + i) * 96 + x0 + j) * 64 + l];
    }
    featp[(((size_t)b * 98 + y + 1) * 98 + x + 1) * 192 + coff + l] = __float2bfloat16(acc);
}

// ---------------- MFMA fuse conv: implicit GEMM M=18432 N=64 K=9*192, NCHW out ----------------
__global__ void fuse_mfma_k(const __hip_bfloat16* __restrict__ featp,
                            const __hip_bfloat16* __restrict__ wt,
                            const float* __restrict__ b_fuse,
                            float* __restrict__ out) {
    int s = blockIdx.x;
    int x0 = (s % 3) * 32;
    int row = s / 3;
    int b = row / 96, y = row - b * 96;
    int tid = threadIdx.x;
    int l = tid & 63, w = tid >> 6;
    int mtile = w >> 1, nbase = (w & 1) * 32;
    int lm = l & 15, g = l >> 4;

    f32x4 acc0 = {0, 0, 0, 0}, acc1 = {0, 0, 0, 0};
    int xa = x0 + mtile * 16 + lm;                     // A row = pixel
    const __hip_bfloat16* fb = featp + (((size_t)b * 98 + (y + 1)) * 98 + (xa + 1)) * 192 + g * 8;
    const __hip_bfloat16* w0 = wt + (size_t)(nbase + lm) * 1728 + g * 8;
    const __hip_bfloat16* w1 = w0 + 16 * 1728;

    for (int tap = 0; tap < 9; ++tap) {
        int dy = tap / 3 - 1, dx = tap % 3 - 1;
        const __hip_bfloat16* ap  = fb + (dy * 98 + dx) * 192;
        const __hip_bfloat16* bp0 = w0 + tap * 192;
        const __hip_bfloat16* bp1 = w1 + tap * 192;
        #pragma unroll
        for (int c0 = 0; c0 < 192; c0 += 32) {
            short8v a  = *reinterpret_cast<const short8v*>(ap + c0);
            short8v b0 = *reinterpret_cast<const short8v*>(bp0 + c0);
            short8v b1 = *reinterpret_cast<const short8v*>(bp1 + c0);
            acc0 = __builtin_amdgcn_mfma_f32_16x16x32_bf16(a, b0, acc0, 0, 0, 0);
            acc1 = __builtin_amdgcn_mfma_f32_16x16x32_bf16(a, b1, acc1, 0, 0, 0);
        }
    }
    int o0 = nbase + lm, o1 = o0 + 16;
    float bias0 = b_fuse[o0], bias1 = b_fuse[o1];
    int mb = x0 + mtile * 16 + g * 4;
    float* outb = out + (size_t)b * 64 * HW + (size_t)y * 96;
    #pragma unroll
    for (int r = 0; r < 4; ++r) {
        int x = mb + r;
        outb[(size_t)o0 * HW + x] = acc0[r] + bias0;
        outb[(size_t)o1 * HW + x] = acc1[r] + bias1;
    }
}

extern "C" void kernel_launch(void* const* d_in, const int* in_sizes, int n_in,
                              void* d_out, int out_size, void* d_ws, size_t ws_size,
                              hipStream_t stream) {
    const float* past     = (const float*)d_in[0];
    const float* curr     = (const float*)d_in[1];
    const float* w_smooth = (const float*)d_in[2];
    const float* b_smooth = (const float*)d_in[3];
    const float* w_reduce = (const float*)d_in[4];
    const float* b_reduce = (const float*)d_in[5];
    const float* w_v0     = (const float*)d_in[6];
    const float* b_v0     = (const float*)d_in[7];
    const float* w_v1     = (const float*)d_in[8];
    const float* b_v1     = (const float*)d_in[9];
    const float* rpb0     = (const float*)d_in[10];
    const float* rpb1     = (const float*)d_in[11];
    const float* w_fuse   = (const float*)d_in[12];
    const float* b_fuse   = (const float*)d_in[13];
    float* out = (float*)d_out;

    const size_t NF = (size_t)NPIX * 64;
    char* p = (char*)d_ws;
    auto carve = [&](size_t bytes) { char* r = p; p += (bytes + 255) & ~(size_t)255; return r; };
    float* past_cl  = (float*)carve(NF * 4);
    float* curr_cl  = (float*)carve(NF * 4);
    float* past2_cl = (float*)carve(NF * 4);
    float* v0_cl    = (float*)carve(NF * 4);
    float* v1_cl    = (float*)carve(NF * 4);
    __hip_bfloat16* featp   = (__hip_bfloat16*)carve((size_t)2 * 98 * 98 * 192 * 2);
    __hip_bfloat16* ps_b    = (__hip_bfloat16*)carve((size_t)NPIX * 128 * 2);
    __hip_bfloat16* past2_b = (__hip_bfloat16*)carve(NF * 2);
    __hip_bfloat16* wt_fuse = (__hip_bfloat16*)carve((size_t)64 * 1728 * 2);
    __hip_bfloat16* wr_b    = (__hip_bfloat16*)carve((size_t)64 * 128 * 2);
    __hip_bfloat16* wv0_b   = (__hip_bfloat16*)carve((size_t)64 * 64 * 2);
    __hip_bfloat16* wv1_b   = (__hip_bfloat16*)carve((size_t)64 * 64 * 2);

    // zero padded feature buffer (border must be 0; interior fully rewritten below)
    hipMemsetAsync(featp, 0, (size_t)2 * 98 * 98 * 192 * 2, stream);
    prep_k<<<432, 256, 0, stream>>>(w_fuse, w_reduce, w_v0, w_v1, wt_fuse, wr_b, wv0_b, wv1_b);

    dim3 tb(32, 8, 1), tg(HW / 32, 2, 4);
    transpose_cl_k<<<tg, tb, 0, stream>>>(past, curr, past_cl, curr_cl, featp, ps_b);
    smooth_k<<<NPIX / 4, 256, 0, stream>>>(past_cl, w_smooth, b_smooth, ps_b);
    reduce_mfma_k<<<NPIX / 32, 256, 0, stream>>>(ps_b, wr_b, b_reduce, past2_cl, past2_b);
    vv_mfma_k<<<NPIX / 32, 256, 0, stream>>>(past2_b, wv0_b, wv1_b, b_v0, b_v1, v0_cl, v1_cl);
    natten_k<3><<<NPIX / 4, 256, 0, stream>>>(curr_cl, past2_cl, v0_cl, rpb0, featp, 64);
    natten_k<7><<<NPIX / 4, 256, 0, stream>>>(curr_cl, past2_cl, v1_cl, rpb1, featp, 128);
    fuse_mfma_k<<<NPIX / 32, 256, 0, stream>>>(featp, wt_fuse, b_fuse, out);
}

// Round 3
// 212.932 us; speedup vs baseline: 3.3759x; 1.5156x over previous
//
#include <hip/hip_runtime.h>
#include <hip/hip_bf16.h>

#define HW 9216
#define NPIX 18432

typedef __attribute__((ext_vector_type(8))) short short8v;
typedef __attribute__((ext_vector_type(4))) float f32x4;

// ---------------- weight prep: bf16 + fuse-weight transpose to [o][tap][c] ----------------
__global__ void prep_k(const float* __restrict__ w_fuse, const float* __restrict__ w_reduce,
                       const float* __restrict__ w_v0, const float* __restrict__ w_v1,
                       __hip_bfloat16* __restrict__ wt_fuse, __hip_bfloat16* __restrict__ wr_b,
                       __hip_bfloat16* __restrict__ wv0_b, __hip_bfloat16* __restrict__ wv1_b) {
    int i = blockIdx.x * 256 + threadIdx.x;
    if (i < 110592) {
        int o = i / 1728, r = i - o * 1728, tap = r / 192, c = r - tap * 192;
        wt_fuse[i] = __float2bfloat16(w_fuse[o * 1728 + c * 9 + tap]);
    }
    if (i < 8192) wr_b[i] = __float2bfloat16(w_reduce[i]);
    if (i < 4096) { wv0_b[i] = __float2bfloat16(w_v0[i]); wv1_b[i] = __float2bfloat16(w_v1[i]); }
}

// ---------------- transpose NCHW -> NHWC (curr); past -> featp(bf16 padded) + past_b ----------------
__global__ void transpose_cl_k(const float* __restrict__ past,
                               const float* __restrict__ curr,
                               float* __restrict__ curr_cl,
                               __hip_bfloat16* __restrict__ featp,
                               __hip_bfloat16* __restrict__ past_b) {
    __shared__ float tile[32][33];
    int t = blockIdx.z & 1, b = blockIdx.z >> 1;
    const float* src = t ? curr : past;
    int p0 = blockIdx.x * 32, c0 = blockIdx.y * 32;
    for (int k = threadIdx.y; k < 32; k += 8)
        tile[k][threadIdx.x] = src[(size_t)(b * 64 + c0 + k) * HW + p0 + threadIdx.x];
    __syncthreads();
    for (int k = threadIdx.y; k < 32; k += 8) {
        float v = tile[threadIdx.x][k];
        int pp = p0 + k;
        if (t) {
            curr_cl[((size_t)b * HW + pp) * 64 + c0 + threadIdx.x] = v;
        } else {
            __hip_bfloat16 hv = __float2bfloat16(v);
            int y = pp / 96, x = pp - (pp / 96) * 96;
            featp[(((size_t)b * 98 + y + 1) * 98 + x + 1) * 192 + c0 + threadIdx.x] = hv;
            past_b[((size_t)b * HW + pp) * 64 + c0 + threadIdx.x] = hv;
        }
    }
}

// ---------------- shift + grouped 3x3 smooth conv: lane=pixel, wave=group ----------------
__global__ __launch_bounds__(512) void smooth_k(const float* __restrict__ past,
                                                const float* __restrict__ w_smooth,
                                                const float* __restrict__ b_smooth,
                                                __hip_bfloat16* __restrict__ smooth_b) {
    int g = threadIdx.x >> 6;                 // wave = group (uniform sy,sx -> no divergence)
    int lane = threadIdx.x & 63;
    int p = blockIdx.x * 64 + lane;           // 64 | 9216 -> strip never crosses batch
    int b = p / HW, rem = p - b * HW;
    int y = rem / 96, x = rem - y * 96;
    int gi = g < 4 ? g : g + 1;               // skip (0,0) in 3x3 row-major
    int sy = gi / 3 - 1, sx = gi % 3 - 1;
    const float* base = past + (size_t)(b * 64 + g * 8) * HW;

    float v[9][8];
    #pragma unroll
    for (int ky = 0; ky < 3; ++ky) {
        #pragma unroll
        for (int kx = 0; kx < 3; ++kx) {
            int yy = y + ky - 1, xx = x + kx - 1;      // conv zero-pad bounds
            int ys = yy - sy, xs = xx - sx;            // shifted-in-zero bounds
            bool ok = (unsigned)yy < 96u && (unsigned)xx < 96u &&
                      (unsigned)ys < 96u && (unsigned)xs < 96u;
            int off = ok ? (ys * 96 + xs) : rem;       // clamped, always in-bounds
            #pragma unroll
            for (int c = 0; c < 8; ++c) {
                float tv = base[(size_t)c * HW + off]; // coalesced: lane-contiguous
                v[ky * 3 + kx][c] = ok ? tv : 0.f;
            }
        }
    }
    float acc[8];
    #pragma unroll
    for (int j = 0; j < 8; ++j) acc[j] = b_smooth[g * 8 + j];
    #pragma unroll
    for (int j = 0; j < 8; ++j) {
        const float* wp = w_smooth + (g * 8 + j) * 72;   // wave-uniform -> s_load
        #pragma unroll
        for (int c = 0; c < 8; ++c)
            #pragma unroll
            for (int t = 0; t < 9; ++t)
                acc[j] += wp[c * 9 + t] * v[t][c];
    }
    short8v pack;
    #pragma unroll
    for (int j = 0; j < 8; ++j) {
        __hip_bfloat16 h = __float2bfloat16(acc[j]);
        pack[j] = *reinterpret_cast<short*>(&h);
    }
    *reinterpret_cast<short8v*>(smooth_b + (size_t)p * 64 + g * 8) = pack;
}

// ---------------- MFMA 1x1 reduce: [past_b|smooth_b] (K=128) x wr_b -> past2 ----------------
__global__ void reduce_mfma_k(const __hip_bfloat16* __restrict__ past_b,
                              const __hip_bfloat16* __restrict__ smooth_b,
                              const __hip_bfloat16* __restrict__ wr_b,
                              const float* __restrict__ b_reduce,
                              float* __restrict__ past2_cl,
                              __hip_bfloat16* __restrict__ past2_b) {
    int p0 = blockIdx.x * 32;
    int tid = threadIdx.x, l = tid & 63, w = tid >> 6;
    int mtile = w >> 1, nbase = (w & 1) * 32;
    int lm = l & 15, g = l >> 4;
    f32x4 acc0 = {0, 0, 0, 0}, acc1 = {0, 0, 0, 0};
    size_t arow = (size_t)(p0 + mtile * 16 + lm) * 64 + g * 8;
    const __hip_bfloat16* b0p = wr_b + (size_t)(nbase + lm) * 128 + g * 8;
    const __hip_bfloat16* b1p = b0p + 16 * 128;
    #pragma unroll
    for (int c0 = 0; c0 < 128; c0 += 32) {
        const __hip_bfloat16* asrc = (c0 < 64) ? (past_b + arow + c0) : (smooth_b + arow + (c0 - 64));
        short8v a  = *reinterpret_cast<const short8v*>(asrc);
        short8v b0 = *reinterpret_cast<const short8v*>(b0p + c0);
        short8v b1 = *reinterpret_cast<const short8v*>(b1p + c0);
        acc0 = __builtin_amdgcn_mfma_f32_16x16x32_bf16(a, b0, acc0, 0, 0, 0);
        acc1 = __builtin_amdgcn_mfma_f32_16x16x32_bf16(a, b1, acc1, 0, 0, 0);
    }
    int o0 = nbase + lm, o1 = o0 + 16;
    float bias0 = b_reduce[o0], bias1 = b_reduce[o1];
    #pragma unroll
    for (int r = 0; r < 4; ++r) {
        int p = p0 + mtile * 16 + g * 4 + r;
        float v0 = acc0[r] + bias0, v1 = acc1[r] + bias1;
        past2_cl[(size_t)p * 64 + o0] = v0;
        past2_cl[(size_t)p * 64 + o1] = v1;
        past2_b[(size_t)p * 64 + o0] = __float2bfloat16(v0);
        past2_b[(size_t)p * 64 + o1] = __float2bfloat16(v1);
    }
}

// ---------------- MFMA both V 1x1 convs ----------------
__global__ void vv_mfma_k(const __hip_bfloat16* __restrict__ past2_b,
                          const __hip_bfloat16* __restrict__ wv0_b,
                          const __hip_bfloat16* __restrict__ wv1_b,
                          const float* __restrict__ b_v0, const float* __restrict__ b_v1,
                          float* __restrict__ v0_cl, float* __restrict__ v1_cl) {
    int p0 = blockIdx.x * 32;
    int tid = threadIdx.x, l = tid & 63, w = tid >> 6;
    int mtile = w >> 1, nbase = (w & 1) * 32;
    int lm = l & 15, g = l >> 4;
    f32x4 acc00 = {0,0,0,0}, acc01 = {0,0,0,0}, acc10 = {0,0,0,0}, acc11 = {0,0,0,0};
    const __hip_bfloat16* ap = past2_b + (size_t)(p0 + mtile * 16 + lm) * 64 + g * 8;
    size_t bo = (size_t)(nbase + lm) * 64 + g * 8;
    #pragma unroll
    for (int c0 = 0; c0 < 64; c0 += 32) {
        short8v a   = *reinterpret_cast<const short8v*>(ap + c0);
        short8v b00 = *reinterpret_cast<const short8v*>(wv0_b + bo + c0);
        short8v b01 = *reinterpret_cast<const short8v*>(wv0_b + bo + 16 * 64 + c0);
        short8v b10 = *reinterpret_cast<const short8v*>(wv1_b + bo + c0);
        short8v b11 = *reinterpret_cast<const short8v*>(wv1_b + bo + 16 * 64 + c0);
        acc00 = __builtin_amdgcn_mfma_f32_16x16x32_bf16(a, b00, acc00, 0, 0, 0);
        acc01 = __builtin_amdgcn_mfma_f32_16x16x32_bf16(a, b01, acc01, 0, 0, 0);
        acc10 = __builtin_amdgcn_mfma_f32_16x16x32_bf16(a, b10, acc10, 0, 0, 0);
        acc11 = __builtin_amdgcn_mfma_f32_16x16x32_bf16(a, b11, acc11, 0, 0, 0);
    }
    int o0 = nbase + lm, o1 = o0 + 16;
    float bi00 = b_v0[o0], bi01 = b_v0[o1], bi10 = b_v1[o0], bi11 = b_v1[o1];
    #pragma unroll
    for (int r = 0; r < 4; ++r) {
        int p = p0 + mtile * 16 + g * 4 + r;
        v0_cl[(size_t)p * 64 + o0] = acc00[r] + bi00;
        v0_cl[(size_t)p * 64 + o1] = acc01[r] + bi01;
        v1_cl[(size_t)p * 64 + o0] = acc10[r] + bi10;
        v1_cl[(size_t)p * 64 + o1] = acc11[r] + bi11;
    }
}

// ---------------- neighborhood attention (clipped window), out -> featp bf16 ----------------
template <int KS>
__global__ void natten_k(const float* __restrict__ q_cl,
                         const float* __restrict__ k_cl,
                         const float* __restrict__ v_cl,
                         const float* __restrict__ rpb,
                         __hip_bfloat16* __restrict__ featp, int coff) {
    constexpr int KK = KS * KS, R = KS / 2, RW = 2 * KS - 1;
    int tid = threadIdx.x;
    int l = tid & 63, wid = tid >> 6;
    int p = blockIdx.x * 4 + wid;
    int b = p / HW, rem = p - b * HW;
    int y = rem / 96, x = rem - y * 96;
    int y0 = y - R; y0 = y0 < 0 ? 0 : (y0 > 96 - KS ? 96 - KS : y0);
    int x0 = x - R; x0 = x0 < 0 ? 0 : (x0 > 96 - KS ? 96 - KS : x0);
    __shared__ float attn_s[4][64];

    // phase 1: lane = neighbor; dot(q, k_n) + rpb (float4-vectorized)
    float sc = -1e30f;
    if (l < KK) {
        int i = l / KS, j = l - i * KS;
        int ky = y0 + i, kx = x0 + j;
        const float4* kp = (const float4*)(k_cl + ((size_t)b * HW + ky * 96 + kx) * 64);
        const float4* qp = (const float4*)(q_cl + (size_t)p * 64);
        float s = 0.f;
        #pragma unroll 4
        for (int c = 0; c < 16; ++c) {
            float4 qv = qp[c], kv = kp[c];
            s += qv.x * kv.x + qv.y * kv.y + qv.z * kv.z + qv.w * kv.w;
        }
        sc = s + rpb[(ky - y + KS - 1) * RW + (kx - x + KS - 1)];
    }
    // wave softmax over KK lanes
    float m = sc;
    for (int off = 32; off; off >>= 1) m = fmaxf(m, __shfl_xor(m, off));
    float e = (l < KK) ? __expf(sc - m) : 0.f;
    float sum = e;
    for (int off = 32; off; off >>= 1) sum += __shfl_xor(sum, off);
    attn_s[wid][l] = e / sum;
    __syncthreads();

    // phase 2: lane = channel
    float acc = 0.f;
    const float* vb = v_cl + (size_t)b * HW * 64;
    for (int n = 0; n < KK; ++n) {
        int i = n / KS, j = n - i * KS;
        acc += attn_s[wid][n] * vb[((y0 + i) * 96 + x0 + j) * 64 + l];
    }
    featp[(((size_t)b * 98 + y + 1) * 98 + x + 1) * 192 + coff + l] = __float2bfloat16(acc);
}

// ---------------- MFMA fuse conv: implicit GEMM M=18432 N=64 K=9*192, NCHW out ----------------
__global__ void fuse_mfma_k(const __hip_bfloat16* __restrict__ featp,
                            const __hip_bfloat16* __restrict__ wt,
                            const float* __restrict__ b_fuse,
                            float* __restrict__ out) {
    int s = blockIdx.x;
    int x0 = (s % 3) * 32;
    int row = s / 3;
    int b = row / 96, y = row - b * 96;
    int tid = threadIdx.x;
    int l = tid & 63, w = tid >> 6;
    int mtile = w >> 1, nbase = (w & 1) * 32;
    int lm = l & 15, g = l >> 4;

    f32x4 acc0 = {0, 0, 0, 0}, acc1 = {0, 0, 0, 0};
    int xa = x0 + mtile * 16 + lm;                     // A row = pixel
    const __hip_bfloat16* fb = featp + (((size_t)b * 98 + (y + 1)) * 98 + (xa + 1)) * 192 + g * 8;
    const __hip_bfloat16* w0 = wt + (size_t)(nbase + lm) * 1728 + g * 8;
    const __hip_bfloat16* w1 = w0 + 16 * 1728;

    for (int tap = 0; tap < 9; ++tap) {
        int dy = tap / 3 - 1, dx = tap % 3 - 1;
        const __hip_bfloat16* ap  = fb + (dy * 98 + dx) * 192;
        const __hip_bfloat16* bp0 = w0 + tap * 192;
        const __hip_bfloat16* bp1 = w1 + tap * 192;
        #pragma unroll
        for (int c0 = 0; c0 < 192; c0 += 32) {
            short8v a  = *reinterpret_cast<const short8v*>(ap + c0);
            short8v b0 = *reinterpret_cast<const short8v*>(bp0 + c0);
            short8v b1 = *reinterpret_cast<const short8v*>(bp1 + c0);
            acc0 = __builtin_amdgcn_mfma_f32_16x16x32_bf16(a, b0, acc0, 0, 0, 0);
            acc1 = __builtin_amdgcn_mfma_f32_16x16x32_bf16(a, b1, acc1, 0, 0, 0);
        }
    }
    int o0 = nbase + lm, o1 = o0 + 16;
    float bias0 = b_fuse[o0], bias1 = b_fuse[o1];
    int mb = x0 + mtile * 16 + g * 4;
    float* outb = out + (size_t)b * 64 * HW + (size_t)y * 96;
    #pragma unroll
    for (int r = 0; r < 4; ++r) {
        int x = mb + r;
        outb[(size_t)o0 * HW + x] = acc0[r] + bias0;
        outb[(size_t)o1 * HW + x] = acc1[r] + bias1;
    }
}

extern "C" void kernel_launch(void* const* d_in, const int* in_sizes, int n_in,
                              void* d_out, int out_size, void* d_ws, size_t ws_size,
                              hipStream_t stream) {
    const float* past     = (const float*)d_in[0];
    const float* curr     = (const float*)d_in[1];
    const float* w_smooth = (const float*)d_in[2];
    const float* b_smooth = (const float*)d_in[3];
    const float* w_reduce = (const float*)d_in[4];
    const float* b_reduce = (const float*)d_in[5];
    const float* w_v0     = (const float*)d_in[6];
    const float* b_v0     = (const float*)d_in[7];
    const float* w_v1     = (const float*)d_in[8];
    const float* b_v1     = (const float*)d_in[9];
    const float* rpb0     = (const float*)d_in[10];
    const float* rpb1     = (const float*)d_in[11];
    const float* w_fuse   = (const float*)d_in[12];
    const float* b_fuse   = (const float*)d_in[13];
    float* out = (float*)d_out;

    const size_t NF = (size_t)NPIX * 64;
    char* p = (char*)d_ws;
    auto carve = [&](size_t bytes) { char* r = p; p += (bytes + 255) & ~(size_t)255; return r; };
    float* curr_cl  = (float*)carve(NF * 4);
    float* past2_cl = (float*)carve(NF * 4);
    float* v0_cl    = (float*)carve(NF * 4);
    float* v1_cl    = (float*)carve(NF * 4);
    __hip_bfloat16* featp    = (__hip_bfloat16*)carve((size_t)2 * 98 * 98 * 192 * 2);
    __hip_bfloat16* past_b   = (__hip_bfloat16*)carve(NF * 2);
    __hip_bfloat16* smooth_b = (__hip_bfloat16*)carve(NF * 2);
    __hip_bfloat16* past2_b  = (__hip_bfloat16*)carve(NF * 2);
    __hip_bfloat16* wt_fuse  = (__hip_bfloat16*)carve((size_t)64 * 1728 * 2);
    __hip_bfloat16* wr_b     = (__hip_bfloat16*)carve((size_t)64 * 128 * 2);
    __hip_bfloat16* wv0_b    = (__hip_bfloat16*)carve((size_t)64 * 64 * 2);
    __hip_bfloat16* wv1_b    = (__hip_bfloat16*)carve((size_t)64 * 64 * 2);

    // zero padded feature buffer (border must be 0; interior fully rewritten below)
    hipMemsetAsync(featp, 0, (size_t)2 * 98 * 98 * 192 * 2, stream);
    prep_k<<<432, 256, 0, stream>>>(w_fuse, w_reduce, w_v0, w_v1, wt_fuse, wr_b, wv0_b, wv1_b);

    dim3 tb(32, 8, 1), tg(HW / 32, 2, 4);
    transpose_cl_k<<<tg, tb, 0, stream>>>(past, curr, curr_cl, featp, past_b);
    smooth_k<<<NPIX / 64, 512, 0, stream>>>(past, w_smooth, b_smooth, smooth_b);
    reduce_mfma_k<<<NPIX / 32, 256, 0, stream>>>(past_b, smooth_b, wr_b, b_reduce, past2_cl, past2_b);
    vv_mfma_k<<<NPIX / 32, 256, 0, stream>>>(past2_b, wv0_b, wv1_b, b_v0, b_v1, v0_cl, v1_cl);
    natten_k<3><<<NPIX / 4, 256, 0, stream>>>(curr_cl, past2_cl, v0_cl, rpb0, featp, 64);
    natten_k<7><<<NPIX / 4, 256, 0, stream>>>(curr_cl, past2_cl, v1_cl, rpb1, featp, 128);
    fuse_mfma_k<<<NPIX / 32, 256, 0, stream>>>(featp, wt_fuse, b_fuse, out);
}

// Round 4
// 174.517 us; speedup vs baseline: 4.1191x; 1.2201x over previous
//
#include <hip/hip_runtime.h>
#include <hip/hip_bf16.h>

#define HW 9216
#define NPIX 18432

typedef __attribute__((ext_vector_type(8))) short short8v;
typedef __attribute__((ext_vector_type(4))) float f32x4;

// ---------------- weight prep: bf16 + fuse-weight transpose to [o][tap][c] ----------------
__global__ void prep_k(const float* __restrict__ w_fuse, const float* __restrict__ w_reduce,
                       const float* __restrict__ w_v0, const float* __restrict__ w_v1,
                       __hip_bfloat16* __restrict__ wt_fuse, __hip_bfloat16* __restrict__ wr_b,
                       __hip_bfloat16* __restrict__ wv0_b, __hip_bfloat16* __restrict__ wv1_b) {
    int i = blockIdx.x * 256 + threadIdx.x;
    if (i < 110592) {
        int o = i / 1728, r = i - o * 1728, tap = r / 192, c = r - tap * 192;
        wt_fuse[i] = __float2bfloat16(w_fuse[o * 1728 + c * 9 + tap]);
    }
    if (i < 8192) wr_b[i] = __float2bfloat16(w_reduce[i]);
    if (i < 4096) { wv0_b[i] = __float2bfloat16(w_v0[i]); wv1_b[i] = __float2bfloat16(w_v1[i]); }
}

// ---------------- transpose NCHW -> bf16 channels-last; past also -> featp + past_b ----------------
__global__ void transpose_cl_k(const float* __restrict__ past,
                               const float* __restrict__ curr,
                               __hip_bfloat16* __restrict__ curr_b,
                               __hip_bfloat16* __restrict__ featp,
                               __hip_bfloat16* __restrict__ past_b) {
    __shared__ float tile[32][33];
    int t = blockIdx.z & 1, b = blockIdx.z >> 1;
    const float* src = t ? curr : past;
    int p0 = blockIdx.x * 32, c0 = blockIdx.y * 32;
    for (int k = threadIdx.y; k < 32; k += 8)
        tile[k][threadIdx.x] = src[(size_t)(b * 64 + c0 + k) * HW + p0 + threadIdx.x];
    __syncthreads();
    for (int k = threadIdx.y; k < 32; k += 8) {
        __hip_bfloat16 hv = __float2bfloat16(tile[threadIdx.x][k]);
        int pp = p0 + k;
        if (t) {
            curr_b[((size_t)b * HW + pp) * 64 + c0 + threadIdx.x] = hv;
        } else {
            int y = pp / 96, x = pp - (pp / 96) * 96;
            featp[(((size_t)b * 98 + y + 1) * 98 + x + 1) * 192 + c0 + threadIdx.x] = hv;
            past_b[((size_t)b * HW + pp) * 64 + c0 + threadIdx.x] = hv;
        }
    }
}

// ---------------- shift + grouped 3x3 smooth conv: lane=pixel, wave=group ----------------
__global__ __launch_bounds__(512) void smooth_k(const float* __restrict__ past,
                                                const float* __restrict__ w_smooth,
                                                const float* __restrict__ b_smooth,
                                                __hip_bfloat16* __restrict__ smooth_b) {
    int g = threadIdx.x >> 6;
    int lane = threadIdx.x & 63;
    int p = blockIdx.x * 64 + lane;
    int b = p / HW, rem = p - b * HW;
    int y = rem / 96, x = rem - y * 96;
    int gi = g < 4 ? g : g + 1;
    int sy = gi / 3 - 1, sx = gi % 3 - 1;
    const float* base = past + (size_t)(b * 64 + g * 8) * HW;

    float v[9][8];
    #pragma unroll
    for (int ky = 0; ky < 3; ++ky) {
        #pragma unroll
        for (int kx = 0; kx < 3; ++kx) {
            int yy = y + ky - 1, xx = x + kx - 1;
            int ys = yy - sy, xs = xx - sx;
            bool ok = (unsigned)yy < 96u && (unsigned)xx < 96u &&
                      (unsigned)ys < 96u && (unsigned)xs < 96u;
            int off = ok ? (ys * 96 + xs) : rem;
            #pragma unroll
            for (int c = 0; c < 8; ++c) {
                float tv = base[(size_t)c * HW + off];
                v[ky * 3 + kx][c] = ok ? tv : 0.f;
            }
        }
    }
    float acc[8];
    #pragma unroll
    for (int j = 0; j < 8; ++j) acc[j] = b_smooth[g * 8 + j];
    #pragma unroll
    for (int j = 0; j < 8; ++j) {
        const float* wp = w_smooth + (g * 8 + j) * 72;
        #pragma unroll
        for (int c = 0; c < 8; ++c)
            #pragma unroll
            for (int t = 0; t < 9; ++t)
                acc[j] += wp[c * 9 + t] * v[t][c];
    }
    short8v pack;
    #pragma unroll
    for (int j = 0; j < 8; ++j) {
        __hip_bfloat16 h = __float2bfloat16(acc[j]);
        pack[j] = *reinterpret_cast<short*>(&h);
    }
    *reinterpret_cast<short8v*>(smooth_b + (size_t)p * 64 + g * 8) = pack;
}

// ---------------- MFMA 1x1 reduce: [past_b|smooth_b] (K=128) x wr_b -> past2_b ----------------
__global__ void reduce_mfma_k(const __hip_bfloat16* __restrict__ past_b,
                              const __hip_bfloat16* __restrict__ smooth_b,
                              const __hip_bfloat16* __restrict__ wr_b,
                              const float* __restrict__ b_reduce,
                              __hip_bfloat16* __restrict__ past2_b) {
    int p0 = blockIdx.x * 32;
    int tid = threadIdx.x, l = tid & 63, w = tid >> 6;
    int mtile = w >> 1, nbase = (w & 1) * 32;
    int lm = l & 15, g = l >> 4;
    f32x4 acc0 = {0, 0, 0, 0}, acc1 = {0, 0, 0, 0};
    size_t arow = (size_t)(p0 + mtile * 16 + lm) * 64 + g * 8;
    const __hip_bfloat16* b0p = wr_b + (size_t)(nbase + lm) * 128 + g * 8;
    const __hip_bfloat16* b1p = b0p + 16 * 128;
    #pragma unroll
    for (int c0 = 0; c0 < 128; c0 += 32) {
        const __hip_bfloat16* asrc = (c0 < 64) ? (past_b + arow + c0) : (smooth_b + arow + (c0 - 64));
        short8v a  = *reinterpret_cast<const short8v*>(asrc);
        short8v b0 = *reinterpret_cast<const short8v*>(b0p + c0);
        short8v b1 = *reinterpret_cast<const short8v*>(b1p + c0);
        acc0 = __builtin_amdgcn_mfma_f32_16x16x32_bf16(a, b0, acc0, 0, 0, 0);
        acc1 = __builtin_amdgcn_mfma_f32_16x16x32_bf16(a, b1, acc1, 0, 0, 0);
    }
    int o0 = nbase + lm, o1 = o0 + 16;
    float bias0 = b_reduce[o0], bias1 = b_reduce[o1];
    #pragma unroll
    for (int r = 0; r < 4; ++r) {
        int p = p0 + mtile * 16 + g * 4 + r;
        past2_b[(size_t)p * 64 + o0] = __float2bfloat16(acc0[r] + bias0);
        past2_b[(size_t)p * 64 + o1] = __float2bfloat16(acc1[r] + bias1);
    }
}

// ---------------- MFMA both V 1x1 convs -> bf16 ----------------
__global__ void vv_mfma_k(const __hip_bfloat16* __restrict__ past2_b,
                          const __hip_bfloat16* __restrict__ wv0_b,
                          const __hip_bfloat16* __restrict__ wv1_b,
                          const float* __restrict__ b_v0, const float* __restrict__ b_v1,
                          __hip_bfloat16* __restrict__ v0_b, __hip_bfloat16* __restrict__ v1_b) {
    int p0 = blockIdx.x * 32;
    int tid = threadIdx.x, l = tid & 63, w = tid >> 6;
    int mtile = w >> 1, nbase = (w & 1) * 32;
    int lm = l & 15, g = l >> 4;
    f32x4 acc00 = {0,0,0,0}, acc01 = {0,0,0,0}, acc10 = {0,0,0,0}, acc11 = {0,0,0,0};
    const __hip_bfloat16* ap = past2_b + (size_t)(p0 + mtile * 16 + lm) * 64 + g * 8;
    size_t bo = (size_t)(nbase + lm) * 64 + g * 8;
    #pragma unroll
    for (int c0 = 0; c0 < 64; c0 += 32) {
        short8v a   = *reinterpret_cast<const short8v*>(ap + c0);
        short8v b00 = *reinterpret_cast<const short8v*>(wv0_b + bo + c0);
        short8v b01 = *reinterpret_cast<const short8v*>(wv0_b + bo + 16 * 64 + c0);
        short8v b10 = *reinterpret_cast<const short8v*>(wv1_b + bo + c0);
        short8v b11 = *reinterpret_cast<const short8v*>(wv1_b + bo + 16 * 64 + c0);
        acc00 = __builtin_amdgcn_mfma_f32_16x16x32_bf16(a, b00, acc00, 0, 0, 0);
        acc01 = __builtin_amdgcn_mfma_f32_16x16x32_bf16(a, b01, acc01, 0, 0, 0);
        acc10 = __builtin_amdgcn_mfma_f32_16x16x32_bf16(a, b10, acc10, 0, 0, 0);
        acc11 = __builtin_amdgcn_mfma_f32_16x16x32_bf16(a, b11, acc11, 0, 0, 0);
    }
    int o0 = nbase + lm, o1 = o0 + 16;
    float bi00 = b_v0[o0], bi01 = b_v0[o1], bi10 = b_v1[o0], bi11 = b_v1[o1];
    #pragma unroll
    for (int r = 0; r < 4; ++r) {
        int p = p0 + mtile * 16 + g * 4 + r;
        v0_b[(size_t)p * 64 + o0] = __float2bfloat16(acc00[r] + bi00);
        v0_b[(size_t)p * 64 + o1] = __float2bfloat16(acc01[r] + bi01);
        v1_b[(size_t)p * 64 + o0] = __float2bfloat16(acc10[r] + bi10);
        v1_b[(size_t)p * 64 + o1] = __float2bfloat16(acc11[r] + bi11);
    }
}

// ---------------- MFMA neighborhood attention: 16-pixel row strip per block ----------------
template <int KS>
__global__ __launch_bounds__(256) void natten_mfma_k(
    const __hip_bfloat16* __restrict__ q_b,
    const __hip_bfloat16* __restrict__ k_b,
    const __hip_bfloat16* __restrict__ v_b,
    const float* __restrict__ rpb,
    __hip_bfloat16* __restrict__ featp, int coff) {
    constexpr int R = KS / 2, RW = 2 * KS - 1;
    constexpr int CW = 16 + KS - 1;            // union col width
    constexpr int NPOS = KS * CW;              // 154 / 54
    constexpr int NPAD = (NPOS + 31) & ~31;    // 160 / 64
    constexpr int NT = NPAD / 16;              // QK n-tiles: 10 / 4
    constexpr int KROW = 72;                   // K_lds row (u16), pad -> 2-way max
    constexpr int VROW = NPAD + 8;             // Vt row (u16)
    constexpr int PROW = NPAD + 8;             // P row (u16)
    constexpr int SROW = NPAD + 1;             // S row (f32), overlays K

    __shared__ __align__(16) char smem[16 * 72 * 2 + NPAD * KROW * 2 + 64 * VROW * 2 +
                                       16 * PROW * 2 + RW * RW * 4];
    __hip_bfloat16* Q  = (__hip_bfloat16*)smem;
    __hip_bfloat16* K  = (__hip_bfloat16*)(smem + 16 * 72 * 2);
    float*          S  = (float*)K;            // overlay after QK MFMAs complete
    __hip_bfloat16* Vt = (__hip_bfloat16*)(smem + 16 * 72 * 2 + NPAD * KROW * 2);
    __hip_bfloat16* P  = (__hip_bfloat16*)((char*)Vt + 64 * VROW * 2);
    float*       rpb_s = (float*)((char*)P + 16 * PROW * 2);

    int blk = blockIdx.x;
    int x0 = (blk % 6) * 16;
    int row = blk / 6;
    int b = row / 96, y = row - b * 96;
    int y0 = y - R;  y0 = y0 < 0 ? 0 : (y0 > 96 - KS ? 96 - KS : y0);
    int c0 = x0 - R; c0 = c0 < 0 ? 0 : (c0 > 96 - KS ? 96 - KS : c0);
    int tid = threadIdx.x;
    size_t plane = (size_t)b * HW;

    // ---- stage Q + rpb ----
    if (tid < 128) {
        int px = tid >> 3, c8 = (tid & 7) * 8;
        *(short8v*)(Q + px * 72 + c8) =
            *(const short8v*)(q_b + (plane + y * 96 + x0 + px) * 64 + c8);
    } else {
        for (int i = tid - 128; i < RW * RW; i += 128) rpb_s[i] = rpb[i];
    }
    // ---- stage K union (zero rows for pos >= NPOS) ----
    for (int pos = tid >> 3; pos < NPAD; pos += 32) {
        int c8 = (tid & 7) * 8;
        short8v val = {0, 0, 0, 0, 0, 0, 0, 0};
        if (pos < NPOS) {
            int i = pos / CW, jc = pos - i * CW;
            int gy = y0 + i;
            int gx = c0 + jc; gx = gx > 95 ? 95 : gx;   // OOB cols masked later
            val = *(const short8v*)(k_b + (plane + gy * 96 + gx) * 64 + c8);
        }
        *(short8v*)(K + pos * KROW + c8) = val;
    }
    // ---- stage V transposed ----
    for (int pos = tid >> 6; pos < NPAD; pos += 4) {
        int c = tid & 63;
        __hip_bfloat16 val = __float2bfloat16(0.f);
        if (pos < NPOS) {
            int i = pos / CW, jc = pos - i * CW;
            int gy = y0 + i;
            int gx = c0 + jc; gx = gx > 95 ? 95 : gx;
            val = v_b[(plane + gy * 96 + gx) * 64 + c];
        }
        Vt[c * VROW + pos] = val;
    }
    __syncthreads();

    int l = tid & 63, w = tid >> 6;
    int lm = l & 15, g = l >> 4;

    // ---- QK^T: wave w handles n-tiles w, w+4, w+8 (static indexing) ----
    short8v qa0 = *(const short8v*)(Q + lm * 72 + g * 8);
    short8v qa1 = *(const short8v*)(Q + lm * 72 + g * 8 + 32);
    f32x4 sacc[3];
    #pragma unroll
    for (int k = 0; k < 3; ++k) {
        int t = w + 4 * k;
        if (t < NT) {
            f32x4 acc = {0, 0, 0, 0};
            const __hip_bfloat16* kp = K + (t * 16 + lm) * KROW + g * 8;
            acc = __builtin_amdgcn_mfma_f32_16x16x32_bf16(qa0, *(const short8v*)kp, acc, 0, 0, 0);
            acc = __builtin_amdgcn_mfma_f32_16x16x32_bf16(qa1, *(const short8v*)(kp + 32), acc, 0, 0, 0);
            sacc[k] = acc;
        }
    }
    __syncthreads();   // all K reads done; S may overwrite K

    // ---- bias + mask -> S ----
    #pragma unroll
    for (int k = 0; k < 3; ++k) {
        int t = w + 4 * k;
        if (t < NT) {
            int pos = t * 16 + lm;
            int i = pos / CW, jc = pos - i * CW;
            int ac = c0 + jc;
            int rel_h = y0 + i - y + KS - 1;
            #pragma unroll
            for (int r = 0; r < 4; ++r) {
                int px = g * 4 + r;
                int x = x0 + px;
                int xw = x - R; xw = xw < 0 ? 0 : (xw > 96 - KS ? 96 - KS : xw);
                int d = ac - xw;
                float sv = -1e30f;
                if (pos < NPOS && (unsigned)d < (unsigned)KS)
                    sv = sacc[k][r] + rpb_s[rel_h * RW + (ac - x + KS - 1)];
                S[px * SROW + pos] = sv;
            }
        }
    }
    __syncthreads();

    // ---- softmax: wave w -> pixels 4w+g; 16 workers (lm) per pixel ----
    {
        int px = 4 * w + g;
        float vals[NT];
        float m = -1e30f;
        #pragma unroll
        for (int k = 0; k < NT; ++k) {
            vals[k] = S[px * SROW + lm + 16 * k];
            m = fmaxf(m, vals[k]);
        }
        #pragma unroll
        for (int off = 1; off < 16; off <<= 1) m = fmaxf(m, __shfl_xor(m, off));
        float sum = 0.f;
        #pragma unroll
        for (int k = 0; k < NT; ++k) { vals[k] = __expf(vals[k] - m); sum += vals[k]; }
        #pragma unroll
        for (int off = 1; off < 16; off <<= 1) sum += __shfl_xor(sum, off);
        float rs = 1.f / sum;
        #pragma unroll
        for (int k = 0; k < NT; ++k)
            P[px * PROW + lm + 16 * k] = __float2bfloat16(vals[k] * rs);
    }
    __syncthreads();

    // ---- PV: wave w -> output channels [16w, 16w+16) ----
    f32x4 oacc = {0, 0, 0, 0};
    #pragma unroll
    for (int kk = 0; kk < NPAD / 32; ++kk) {
        short8v pa = *(const short8v*)(P + lm * PROW + kk * 32 + g * 8);
        short8v vb = *(const short8v*)(Vt + (w * 16 + lm) * VROW + kk * 32 + g * 8);
        oacc = __builtin_amdgcn_mfma_f32_16x16x32_bf16(pa, vb, oacc, 0, 0, 0);
    }
    __hip_bfloat16* ob = featp + (((size_t)b * 98 + y + 1) * 98 + (x0 + 1)) * 192 + coff + w * 16 + lm;
    #pragma unroll
    for (int r = 0; r < 4; ++r) {
        int px = g * 4 + r;
        ob[(size_t)px * 192] = __float2bfloat16(oacc[r]);
    }
}

// ---------------- MFMA fuse conv: implicit GEMM M=18432 N=64 K=9*192, NCHW out ----------------
__global__ void fuse_mfma_k(const __hip_bfloat16* __restrict__ featp,
                            const __hip_bfloat16* __restrict__ wt,
                            const float* __restrict__ b_fuse,
                            float* __restrict__ out) {
    int s = blockIdx.x;
    int x0 = (s % 3) * 32;
    int row = s / 3;
    int b = row / 96, y = row - b * 96;
    int tid = threadIdx.x;
    int l = tid & 63, w = tid >> 6;
    int mtile = w >> 1, nbase = (w & 1) * 32;
    int lm = l & 15, g = l >> 4;

    f32x4 acc0 = {0, 0, 0, 0}, acc1 = {0, 0, 0, 0};
    int xa = x0 + mtile * 16 + lm;
    const __hip_bfloat16* fb = featp + (((size_t)b * 98 + (y + 1)) * 98 + (xa + 1)) * 192 + g * 8;
    const __hip_bfloat16* w0 = wt + (size_t)(nbase + lm) * 1728 + g * 8;
    const __hip_bfloat16* w1 = w0 + 16 * 1728;

    for (int tap = 0; tap < 9; ++tap) {
        int dy = tap / 3 - 1, dx = tap % 3 - 1;
        const __hip_bfloat16* ap  = fb + (dy * 98 + dx) * 192;
        const __hip_bfloat16* bp0 = w0 + tap * 192;
        const __hip_bfloat16* bp1 = w1 + tap * 192;
        #pragma unroll
        for (int c0 = 0; c0 < 192; c0 += 32) {
            short8v a  = *reinterpret_cast<const short8v*>(ap + c0);
            short8v b0 = *reinterpret_cast<const short8v*>(bp0 + c0);
            short8v b1 = *reinterpret_cast<const short8v*>(bp1 + c0);
            acc0 = __builtin_amdgcn_mfma_f32_16x16x32_bf16(a, b0, acc0, 0, 0, 0);
            acc1 = __builtin_amdgcn_mfma_f32_16x16x32_bf16(a, b1, acc1, 0, 0, 0);
        }
    }
    int o0 = nbase + lm, o1 = o0 + 16;
    float bias0 = b_fuse[o0], bias1 = b_fuse[o1];
    int mb = x0 + mtile * 16 + g * 4;
    float* outb = out + (size_t)b * 64 * HW + (size_t)y * 96;
    #pragma unroll
    for (int r = 0; r < 4; ++r) {
        int x = mb + r;
        outb[(size_t)o0 * HW + x] = acc0[r] + bias0;
        outb[(size_t)o1 * HW + x] = acc1[r] + bias1;
    }
}

extern "C" void kernel_launch(void* const* d_in, const int* in_sizes, int n_in,
                              void* d_out, int out_size, void* d_ws, size_t ws_size,
                              hipStream_t stream) {
    const float* past     = (const float*)d_in[0];
    const float* curr     = (const float*)d_in[1];
    const float* w_smooth = (const float*)d_in[2];
    const float* b_smooth = (const float*)d_in[3];
    const float* w_reduce = (const float*)d_in[4];
    const float* b_reduce = (const float*)d_in[5];
    const float* w_v0     = (const float*)d_in[6];
    const float* b_v0     = (const float*)d_in[7];
    const float* w_v1     = (const float*)d_in[8];
    const float* b_v1     = (const float*)d_in[9];
    const float* rpb0     = (const float*)d_in[10];
    const float* rpb1     = (const float*)d_in[11];
    const float* w_fuse   = (const float*)d_in[12];
    const float* b_fuse   = (const float*)d_in[13];
    float* out = (float*)d_out;

    const size_t NF = (size_t)NPIX * 64;
    char* p = (char*)d_ws;
    auto carve = [&](size_t bytes) { char* r = p; p += (bytes + 255) & ~(size_t)255; return r; };
    __hip_bfloat16* featp    = (__hip_bfloat16*)carve((size_t)2 * 98 * 98 * 192 * 2);
    __hip_bfloat16* curr_b   = (__hip_bfloat16*)carve(NF * 2);
    __hip_bfloat16* past_b   = (__hip_bfloat16*)carve(NF * 2);
    __hip_bfloat16* smooth_b = (__hip_bfloat16*)carve(NF * 2);
    __hip_bfloat16* past2_b  = (__hip_bfloat16*)carve(NF * 2);
    __hip_bfloat16* v0_b     = (__hip_bfloat16*)carve(NF * 2);
    __hip_bfloat16* v1_b     = (__hip_bfloat16*)carve(NF * 2);
    __hip_bfloat16* wt_fuse  = (__hip_bfloat16*)carve((size_t)64 * 1728 * 2);
    __hip_bfloat16* wr_b     = (__hip_bfloat16*)carve((size_t)64 * 128 * 2);
    __hip_bfloat16* wv0_b    = (__hip_bfloat16*)carve((size_t)64 * 64 * 2);
    __hip_bfloat16* wv1_b    = (__hip_bfloat16*)carve((size_t)64 * 64 * 2);

    hipMemsetAsync(featp, 0, (size_t)2 * 98 * 98 * 192 * 2, stream);
    prep_k<<<432, 256, 0, stream>>>(w_fuse, w_reduce, w_v0, w_v1, wt_fuse, wr_b, wv0_b, wv1_b);

    dim3 tb(32, 8, 1), tg(HW / 32, 2, 4);
    transpose_cl_k<<<tg, tb, 0, stream>>>(past, curr, curr_b, featp, past_b);
    smooth_k<<<NPIX / 64, 512, 0, stream>>>(past, w_smooth, b_smooth, smooth_b);
    reduce_mfma_k<<<NPIX / 32, 256, 0, stream>>>(past_b, smooth_b, wr_b, b_reduce, past2_b);
    vv_mfma_k<<<NPIX / 32, 256, 0, stream>>>(past2_b, wv0_b, wv1_b, b_v0, b_v1, v0_b, v1_b);
    natten_mfma_k<3><<<NPIX / 16, 256, 0, stream>>>(curr_b, past2_b, v0_b, rpb0, featp, 64);
    natten_mfma_k<7><<<NPIX / 16, 256, 0, stream>>>(curr_b, past2_b, v1_b, rpb1, featp, 128);
    fuse_mfma_k<<<NPIX / 32, 256, 0, stream>>>(featp, wt_fuse, b_fuse, out);
}

// Round 5
// 166.868 us; speedup vs baseline: 4.3079x; 1.0458x over previous
//
#include <hip/hip_runtime.h>
#include <hip/hip_bf16.h>

#define HW 9216
#define NPIX 18432

typedef __attribute__((ext_vector_type(8))) short short8v;
typedef __attribute__((ext_vector_type(4))) float f32x4;

// ---------------- weight prep: bf16 + fuse-weight transpose to [o][tap][c] ----------------
__global__ void prep_k(const float* __restrict__ w_fuse, const float* __restrict__ w_reduce,
                       const float* __restrict__ w_v0, const float* __restrict__ w_v1,
                       __hip_bfloat16* __restrict__ wt_fuse, __hip_bfloat16* __restrict__ wr_b,
                       __hip_bfloat16* __restrict__ wv0_b, __hip_bfloat16* __restrict__ wv1_b) {
    int i = blockIdx.x * 256 + threadIdx.x;
    if (i < 110592) {
        int o = i / 1728, r = i - o * 1728, tap = r / 192, c = r - tap * 192;
        wt_fuse[i] = __float2bfloat16(w_fuse[o * 1728 + c * 9 + tap]);
    }
    if (i < 8192) wr_b[i] = __float2bfloat16(w_reduce[i]);
    if (i < 4096) { wv0_b[i] = __float2bfloat16(w_v0[i]); wv1_b[i] = __float2bfloat16(w_v1[i]); }
}

// ---------------- transpose NCHW -> bf16 channels-last; past also -> featp + past_b ----------------
__global__ void transpose_cl_k(const float* __restrict__ past,
                               const float* __restrict__ curr,
                               __hip_bfloat16* __restrict__ curr_b,
                               __hip_bfloat16* __restrict__ featp,
                               __hip_bfloat16* __restrict__ past_b) {
    __shared__ float tile[32][33];
    int t = blockIdx.z & 1, b = blockIdx.z >> 1;
    const float* src = t ? curr : past;
    int p0 = blockIdx.x * 32, c0 = blockIdx.y * 32;
    for (int k = threadIdx.y; k < 32; k += 8)
        tile[k][threadIdx.x] = src[(size_t)(b * 64 + c0 + k) * HW + p0 + threadIdx.x];
    __syncthreads();
    for (int k = threadIdx.y; k < 32; k += 8) {
        __hip_bfloat16 hv = __float2bfloat16(tile[threadIdx.x][k]);
        int pp = p0 + k;
        if (t) {
            curr_b[((size_t)b * HW + pp) * 64 + c0 + threadIdx.x] = hv;
        } else {
            int y = pp / 96, x = pp - (pp / 96) * 96;
            featp[(((size_t)b * 98 + y + 1) * 98 + x + 1) * 192 + c0 + threadIdx.x] = hv;
            past_b[((size_t)b * HW + pp) * 64 + c0 + threadIdx.x] = hv;
        }
    }
}

// ---------------- shift + grouped 3x3 smooth conv: lane=pixel, wave=group ----------------
__global__ __launch_bounds__(512) void smooth_k(const float* __restrict__ past,
                                                const float* __restrict__ w_smooth,
                                                const float* __restrict__ b_smooth,
                                                __hip_bfloat16* __restrict__ smooth_b) {
    int g = threadIdx.x >> 6;
    int lane = threadIdx.x & 63;
    int p = blockIdx.x * 64 + lane;
    int b = p / HW, rem = p - b * HW;
    int y = rem / 96, x = rem - y * 96;
    int gi = g < 4 ? g : g + 1;
    int sy = gi / 3 - 1, sx = gi % 3 - 1;
    const float* base = past + (size_t)(b * 64 + g * 8) * HW;

    float v[9][8];
    #pragma unroll
    for (int ky = 0; ky < 3; ++ky) {
        #pragma unroll
        for (int kx = 0; kx < 3; ++kx) {
            int yy = y + ky - 1, xx = x + kx - 1;
            int ys = yy - sy, xs = xx - sx;
            bool ok = (unsigned)yy < 96u && (unsigned)xx < 96u &&
                      (unsigned)ys < 96u && (unsigned)xs < 96u;
            int off = ok ? (ys * 96 + xs) : rem;
            #pragma unroll
            for (int c = 0; c < 8; ++c) {
                float tv = base[(size_t)c * HW + off];
                v[ky * 3 + kx][c] = ok ? tv : 0.f;
            }
        }
    }
    float acc[8];
    #pragma unroll
    for (int j = 0; j < 8; ++j) acc[j] = b_smooth[g * 8 + j];
    #pragma unroll
    for (int j = 0; j < 8; ++j) {
        const float* wp = w_smooth + (g * 8 + j) * 72;
        #pragma unroll
        for (int c = 0; c < 8; ++c)
            #pragma unroll
            for (int t = 0; t < 9; ++t)
                acc[j] += wp[c * 9 + t] * v[t][c];
    }
    short8v pack;
    #pragma unroll
    for (int j = 0; j < 8; ++j) {
        __hip_bfloat16 h = __float2bfloat16(acc[j]);
        pack[j] = *reinterpret_cast<short*>(&h);
    }
    *reinterpret_cast<short8v*>(smooth_b + (size_t)p * 64 + g * 8) = pack;
}

// ---------------- MFMA 1x1 reduce: [past_b|smooth_b] (K=128) x wr_b -> past2_b ----------------
__global__ void reduce_mfma_k(const __hip_bfloat16* __restrict__ past_b,
                              const __hip_bfloat16* __restrict__ smooth_b,
                              const __hip_bfloat16* __restrict__ wr_b,
                              const float* __restrict__ b_reduce,
                              __hip_bfloat16* __restrict__ past2_b) {
    int p0 = blockIdx.x * 32;
    int tid = threadIdx.x, l = tid & 63, w = tid >> 6;
    int mtile = w >> 1, nbase = (w & 1) * 32;
    int lm = l & 15, g = l >> 4;
    f32x4 acc0 = {0, 0, 0, 0}, acc1 = {0, 0, 0, 0};
    size_t arow = (size_t)(p0 + mtile * 16 + lm) * 64 + g * 8;
    const __hip_bfloat16* b0p = wr_b + (size_t)(nbase + lm) * 128 + g * 8;
    const __hip_bfloat16* b1p = b0p + 16 * 128;
    #pragma unroll
    for (int c0 = 0; c0 < 128; c0 += 32) {
        const __hip_bfloat16* asrc = (c0 < 64) ? (past_b + arow + c0) : (smooth_b + arow + (c0 - 64));
        short8v a  = *reinterpret_cast<const short8v*>(asrc);
        short8v b0 = *reinterpret_cast<const short8v*>(b0p + c0);
        short8v b1 = *reinterpret_cast<const short8v*>(b1p + c0);
        acc0 = __builtin_amdgcn_mfma_f32_16x16x32_bf16(a, b0, acc0, 0, 0, 0);
        acc1 = __builtin_amdgcn_mfma_f32_16x16x32_bf16(a, b1, acc1, 0, 0, 0);
    }
    int o0 = nbase + lm, o1 = o0 + 16;
    float bias0 = b_reduce[o0], bias1 = b_reduce[o1];
    #pragma unroll
    for (int r = 0; r < 4; ++r) {
        int p = p0 + mtile * 16 + g * 4 + r;
        past2_b[(size_t)p * 64 + o0] = __float2bfloat16(acc0[r] + bias0);
        past2_b[(size_t)p * 64 + o1] = __float2bfloat16(acc1[r] + bias1);
    }
}

// ---------------- MFMA both V 1x1 convs -> bf16 ----------------
__global__ void vv_mfma_k(const __hip_bfloat16* __restrict__ past2_b,
                          const __hip_bfloat16* __restrict__ wv0_b,
                          const __hip_bfloat16* __restrict__ wv1_b,
                          const float* __restrict__ b_v0, const float* __restrict__ b_v1,
                          __hip_bfloat16* __restrict__ v0_b, __hip_bfloat16* __restrict__ v1_b) {
    int p0 = blockIdx.x * 32;
    int tid = threadIdx.x, l = tid & 63, w = tid >> 6;
    int mtile = w >> 1, nbase = (w & 1) * 32;
    int lm = l & 15, g = l >> 4;
    f32x4 acc00 = {0,0,0,0}, acc01 = {0,0,0,0}, acc10 = {0,0,0,0}, acc11 = {0,0,0,0};
    const __hip_bfloat16* ap = past2_b + (size_t)(p0 + mtile * 16 + lm) * 64 + g * 8;
    size_t bo = (size_t)(nbase + lm) * 64 + g * 8;
    #pragma unroll
    for (int c0 = 0; c0 < 64; c0 += 32) {
        short8v a   = *reinterpret_cast<const short8v*>(ap + c0);
        short8v b00 = *reinterpret_cast<const short8v*>(wv0_b + bo + c0);
        short8v b01 = *reinterpret_cast<const short8v*>(wv0_b + bo + 16 * 64 + c0);
        short8v b10 = *reinterpret_cast<const short8v*>(wv1_b + bo + c0);
        short8v b11 = *reinterpret_cast<const short8v*>(wv1_b + bo + 16 * 64 + c0);
        acc00 = __builtin_amdgcn_mfma_f32_16x16x32_bf16(a, b00, acc00, 0, 0, 0);
        acc01 = __builtin_amdgcn_mfma_f32_16x16x32_bf16(a, b01, acc01, 0, 0, 0);
        acc10 = __builtin_amdgcn_mfma_f32_16x16x32_bf16(a, b10, acc10, 0, 0, 0);
        acc11 = __builtin_amdgcn_mfma_f32_16x16x32_bf16(a, b11, acc11, 0, 0, 0);
    }
    int o0 = nbase + lm, o1 = o0 + 16;
    float bi00 = b_v0[o0], bi01 = b_v0[o1], bi10 = b_v1[o0], bi11 = b_v1[o1];
    #pragma unroll
    for (int r = 0; r < 4; ++r) {
        int p = p0 + mtile * 16 + g * 4 + r;
        v0_b[(size_t)p * 64 + o0] = __float2bfloat16(acc00[r] + bi00);
        v0_b[(size_t)p * 64 + o1] = __float2bfloat16(acc01[r] + bi01);
        v1_b[(size_t)p * 64 + o0] = __float2bfloat16(acc10[r] + bi10);
        v1_b[(size_t)p * 64 + o1] = __float2bfloat16(acc11[r] + bi11);
    }
}

// ---------------- MFMA neighborhood attention: 16-pixel row strip per block ----------------
template <int KS>
__global__ __launch_bounds__(256) void natten_mfma_k(
    const __hip_bfloat16* __restrict__ q_b,
    const __hip_bfloat16* __restrict__ k_b,
    const __hip_bfloat16* __restrict__ v_b,
    const float* __restrict__ rpb,
    __hip_bfloat16* __restrict__ featp, int coff) {
    constexpr int R = KS / 2, RW = 2 * KS - 1;
    constexpr int CW = 16 + KS - 1;            // union col width
    constexpr int NPOS = KS * CW;              // 154 / 54
    constexpr int NPAD = (NPOS + 31) & ~31;    // 160 / 64
    constexpr int NT = NPAD / 16;              // QK n-tiles: 10 / 4
    constexpr int KROW = 72;                   // K_lds row (u16), pad -> 2-way max
    constexpr int VROW = NPAD + 8;             // Vt row (u16)
    constexpr int PROW = NPAD + 8;             // P row (u16)
    constexpr int SROW = NPAD + 1;             // S row (f32), overlays K

    __shared__ __align__(16) char smem[16 * 72 * 2 + NPAD * KROW * 2 + 64 * VROW * 2 +
                                       16 * PROW * 2 + RW * RW * 4];
    __hip_bfloat16* Q  = (__hip_bfloat16*)smem;
    __hip_bfloat16* K  = (__hip_bfloat16*)(smem + 16 * 72 * 2);
    float*          S  = (float*)K;            // overlay after QK MFMAs complete
    __hip_bfloat16* Vt = (__hip_bfloat16*)(smem + 16 * 72 * 2 + NPAD * KROW * 2);
    __hip_bfloat16* P  = (__hip_bfloat16*)((char*)Vt + 64 * VROW * 2);
    float*       rpb_s = (float*)((char*)P + 16 * PROW * 2);

    int blk = blockIdx.x;
    int x0 = (blk % 6) * 16;
    int row = blk / 6;
    int b = row / 96, y = row - b * 96;
    int y0 = y - R;  y0 = y0 < 0 ? 0 : (y0 > 96 - KS ? 96 - KS : y0);
    int c0 = x0 - R; c0 = c0 < 0 ? 0 : (c0 > 96 - KS ? 96 - KS : c0);
    int tid = threadIdx.x;
    size_t plane = (size_t)b * HW;

    // ---- stage Q + rpb ----
    if (tid < 128) {
        int px = tid >> 3, c8 = (tid & 7) * 8;
        *(short8v*)(Q + px * 72 + c8) =
            *(const short8v*)(q_b + (plane + y * 96 + x0 + px) * 64 + c8);
    } else {
        for (int i = tid - 128; i < RW * RW; i += 128) rpb_s[i] = rpb[i];
    }
    // ---- stage K union (zero rows for pos >= NPOS) ----
    for (int pos = tid >> 3; pos < NPAD; pos += 32) {
        int c8 = (tid & 7) * 8;
        short8v val = {0, 0, 0, 0, 0, 0, 0, 0};
        if (pos < NPOS) {
            int i = pos / CW, jc = pos - i * CW;
            int gy = y0 + i;
            int gx = c0 + jc; gx = gx > 95 ? 95 : gx;   // OOB cols masked later
            val = *(const short8v*)(k_b + (plane + gy * 96 + gx) * 64 + c8);
        }
        *(short8v*)(K + pos * KROW + c8) = val;
    }
    // ---- stage V transposed ----
    for (int pos = tid >> 6; pos < NPAD; pos += 4) {
        int c = tid & 63;
        __hip_bfloat16 val = __float2bfloat16(0.f);
        if (pos < NPOS) {
            int i = pos / CW, jc = pos - i * CW;
            int gy = y0 + i;
            int gx = c0 + jc; gx = gx > 95 ? 95 : gx;
            val = v_b[(plane + gy * 96 + gx) * 64 + c];
        }
        Vt[c * VROW + pos] = val;
    }
    __syncthreads();

    int l = tid & 63, w = tid >> 6;
    int lm = l & 15, g = l >> 4;

    // ---- QK^T: wave w handles n-tiles w, w+4, w+8 (static indexing) ----
    short8v qa0 = *(const short8v*)(Q + lm * 72 + g * 8);
    short8v qa1 = *(const short8v*)(Q + lm * 72 + g * 8 + 32);
    f32x4 sacc[3];
    #pragma unroll
    for (int k = 0; k < 3; ++k) {
        int t = w + 4 * k;
        if (t < NT) {
            f32x4 acc = {0, 0, 0, 0};
            const __hip_bfloat16* kp = K + (t * 16 + lm) * KROW + g * 8;
            acc = __builtin_amdgcn_mfma_f32_16x16x32_bf16(qa0, *(const short8v*)kp, acc, 0, 0, 0);
            acc = __builtin_amdgcn_mfma_f32_16x16x32_bf16(qa1, *(const short8v*)(kp + 32), acc, 0, 0, 0);
            sacc[k] = acc;
        }
    }
    __syncthreads();   // all K reads done; S may overwrite K

    // ---- bias + mask -> S ----
    #pragma unroll
    for (int k = 0; k < 3; ++k) {
        int t = w + 4 * k;
        if (t < NT) {
            int pos = t * 16 + lm;
            int i = pos / CW, jc = pos - i * CW;
            int ac = c0 + jc;
            int rel_h = y0 + i - y + KS - 1;
            #pragma unroll
            for (int r = 0; r < 4; ++r) {
                int px = g * 4 + r;
                int x = x0 + px;
                int xw = x - R; xw = xw < 0 ? 0 : (xw > 96 - KS ? 96 - KS : xw);
                int d = ac - xw;
                float sv = -1e30f;
                if (pos < NPOS && (unsigned)d < (unsigned)KS)
                    sv = sacc[k][r] + rpb_s[rel_h * RW + (ac - x + KS - 1)];
                S[px * SROW + pos] = sv;
            }
        }
    }
    __syncthreads();

    // ---- softmax: wave w -> pixels 4w+g; 16 workers (lm) per pixel ----
    {
        int px = 4 * w + g;
        float vals[NT];
        float m = -1e30f;
        #pragma unroll
        for (int k = 0; k < NT; ++k) {
            vals[k] = S[px * SROW + lm + 16 * k];
            m = fmaxf(m, vals[k]);
        }
        #pragma unroll
        for (int off = 1; off < 16; off <<= 1) m = fmaxf(m, __shfl_xor(m, off));
        float sum = 0.f;
        #pragma unroll
        for (int k = 0; k < NT; ++k) { vals[k] = __expf(vals[k] - m); sum += vals[k]; }
        #pragma unroll
        for (int off = 1; off < 16; off <<= 1) sum += __shfl_xor(sum, off);
        float rs = 1.f / sum;
        #pragma unroll
        for (int k = 0; k < NT; ++k)
            P[px * PROW + lm + 16 * k] = __float2bfloat16(vals[k] * rs);
    }
    __syncthreads();

    // ---- PV: wave w -> output channels [16w, 16w+16) ----
    f32x4 oacc = {0, 0, 0, 0};
    #pragma unroll
    for (int kk = 0; kk < NPAD / 32; ++kk) {
        short8v pa = *(const short8v*)(P + lm * PROW + kk * 32 + g * 8);
        short8v vb = *(const short8v*)(Vt + (w * 16 + lm) * VROW + kk * 32 + g * 8);
        oacc = __builtin_amdgcn_mfma_f32_16x16x32_bf16(pa, vb, oacc, 0, 0, 0);
    }
    __hip_bfloat16* ob = featp + (((size_t)b * 98 + y + 1) * 98 + (x0 + 1)) * 192 + coff + w * 16 + lm;
    #pragma unroll
    for (int r = 0; r < 4; ++r) {
        int px = g * 4 + r;
        ob[(size_t)px * 192] = __float2bfloat16(oacc[r]);
    }
}

// ---------------- fuse conv stage 1: split-K by dy; partial[dy][p][o] f32 ----------------
__global__ __launch_bounds__(256) void fuse_s1_k(const __hip_bfloat16* __restrict__ featp,
                                                 const __hip_bfloat16* __restrict__ wt,
                                                 float* __restrict__ partial) {
    int blk = blockIdx.x;
    int dy = blk / 576 - 1;        // -1, 0, 1
    int mt = blk - (dy + 1) * 576;
    int x0 = (mt % 3) * 32;
    int row = mt / 3;
    int b = row / 96, y = row - b * 96;
    int tid = threadIdx.x;
    int l = tid & 63, w = tid >> 6;
    int mtile = w >> 1, nbase = (w & 1) * 32;
    int lm = l & 15, g = l >> 4;

    f32x4 acc0 = {0, 0, 0, 0}, acc1 = {0, 0, 0, 0};
    int xa = x0 + mtile * 16 + lm;
    const __hip_bfloat16* fb = featp + (((size_t)b * 98 + (y + 1 + dy)) * 98 + (xa + 1)) * 192 + g * 8;
    const __hip_bfloat16* w0 = wt + (size_t)(nbase + lm) * 1728 + (dy + 1) * 3 * 192 + g * 8;
    const __hip_bfloat16* w1 = w0 + 16 * 1728;

    #pragma unroll
    for (int tx = 0; tx < 3; ++tx) {
        const __hip_bfloat16* ap  = fb + (tx - 1) * 192;
        const __hip_bfloat16* bp0 = w0 + tx * 192;
        const __hip_bfloat16* bp1 = w1 + tx * 192;
        #pragma unroll
        for (int c0 = 0; c0 < 192; c0 += 32) {
            short8v a  = *reinterpret_cast<const short8v*>(ap + c0);
            short8v b0 = *reinterpret_cast<const short8v*>(bp0 + c0);
            short8v b1 = *reinterpret_cast<const short8v*>(bp1 + c0);
            acc0 = __builtin_amdgcn_mfma_f32_16x16x32_bf16(a, b0, acc0, 0, 0, 0);
            acc1 = __builtin_amdgcn_mfma_f32_16x16x32_bf16(a, b1, acc1, 0, 0, 0);
        }
    }
    int o0 = nbase + lm, o1 = o0 + 16;
    float* pd = partial + (size_t)(dy + 1) * NPIX * 64;
    int pbase = row * 96 + x0 + mtile * 16 + g * 4;
    #pragma unroll
    for (int r = 0; r < 4; ++r) {
        size_t prow = (size_t)(pbase + r) * 64;
        pd[prow + o0] = acc0[r];
        pd[prow + o1] = acc1[r];
    }
}

// ---------------- fuse stage 2: sum partials + bias, transpose -> NCHW ----------------
__global__ __launch_bounds__(256) void fuse_s2_k(const float* __restrict__ partial,
                                                 const float* __restrict__ b_fuse,
                                                 float* __restrict__ out) {
    __shared__ float tile[64][65];
    int p0 = blockIdx.x * 64;                  // 64 | 9216: never crosses batch
    int b = p0 / HW, prem = p0 - b * HW;
    int o = threadIdx.x & 63, wr = threadIdx.x >> 6;
    float bias = b_fuse[o];
    for (int i = wr; i < 64; i += 4) {
        size_t idx = (size_t)(p0 + i) * 64 + o;
        tile[i][o] = partial[idx] + partial[(size_t)NPIX * 64 + idx] +
                     partial[(size_t)2 * NPIX * 64 + idx] + bias;
    }
    __syncthreads();
    for (int i = wr; i < 64; i += 4)
        out[((size_t)(b * 64 + i) * HW) + prem + o] = tile[o][i];
}

extern "C" void kernel_launch(void* const* d_in, const int* in_sizes, int n_in,
                              void* d_out, int out_size, void* d_ws, size_t ws_size,
                              hipStream_t stream) {
    const float* past     = (const float*)d_in[0];
    const float* curr     = (const float*)d_in[1];
    const float* w_smooth = (const float*)d_in[2];
    const float* b_smooth = (const float*)d_in[3];
    const float* w_reduce = (const float*)d_in[4];
    const float* b_reduce = (const float*)d_in[5];
    const float* w_v0     = (const float*)d_in[6];
    const float* b_v0     = (const float*)d_in[7];
    const float* w_v1     = (const float*)d_in[8];
    const float* b_v1     = (const float*)d_in[9];
    const float* rpb0     = (const float*)d_in[10];
    const float* rpb1     = (const float*)d_in[11];
    const float* w_fuse   = (const float*)d_in[12];
    const float* b_fuse   = (const float*)d_in[13];
    float* out = (float*)d_out;

    const size_t NF = (size_t)NPIX * 64;
    char* p = (char*)d_ws;
    auto carve = [&](size_t bytes) { char* r = p; p += (bytes + 255) & ~(size_t)255; return r; };
    __hip_bfloat16* featp    = (__hip_bfloat16*)carve((size_t)2 * 98 * 98 * 192 * 2);
    float*          partial  = (float*)carve((size_t)3 * NF * 4);
    __hip_bfloat16* curr_b   = (__hip_bfloat16*)carve(NF * 2);
    __hip_bfloat16* past_b   = (__hip_bfloat16*)carve(NF * 2);
    __hip_bfloat16* smooth_b = (__hip_bfloat16*)carve(NF * 2);
    __hip_bfloat16* past2_b  = (__hip_bfloat16*)carve(NF * 2);
    __hip_bfloat16* v0_b     = (__hip_bfloat16*)carve(NF * 2);
    __hip_bfloat16* v1_b     = (__hip_bfloat16*)carve(NF * 2);
    __hip_bfloat16* wt_fuse  = (__hip_bfloat16*)carve((size_t)64 * 1728 * 2);
    __hip_bfloat16* wr_b     = (__hip_bfloat16*)carve((size_t)64 * 128 * 2);
    __hip_bfloat16* wv0_b    = (__hip_bfloat16*)carve((size_t)64 * 64 * 2);
    __hip_bfloat16* wv1_b    = (__hip_bfloat16*)carve((size_t)64 * 64 * 2);

    hipMemsetAsync(featp, 0, (size_t)2 * 98 * 98 * 192 * 2, stream);
    prep_k<<<432, 256, 0, stream>>>(w_fuse, w_reduce, w_v0, w_v1, wt_fuse, wr_b, wv0_b, wv1_b);

    dim3 tb(32, 8, 1), tg(HW / 32, 2, 4);
    transpose_cl_k<<<tg, tb, 0, stream>>>(past, curr, curr_b, featp, past_b);
    smooth_k<<<NPIX / 64, 512, 0, stream>>>(past, w_smooth, b_smooth, smooth_b);
    reduce_mfma_k<<<NPIX / 32, 256, 0, stream>>>(past_b, smooth_b, wr_b, b_reduce, past2_b);
    vv_mfma_k<<<NPIX / 32, 256, 0, stream>>>(past2_b, wv0_b, wv1_b, b_v0, b_v1, v0_b, v1_b);
    natten_mfma_k<3><<<NPIX / 16, 256, 0, stream>>>(curr_b, past2_b, v0_b, rpb0, featp, 64);
    natten_mfma_k<7><<<NPIX / 16, 256, 0, stream>>>(curr_b, past2_b, v1_b, rpb1, featp, 128);
    fuse_s1_k<<<3 * 576, 256, 0, stream>>>(featp, wt_fuse, partial);
    fuse_s2_k<<<NPIX / 64, 256, 0, stream>>>(partial, b_fuse, out);
}

// Round 6
// 149.715 us; speedup vs baseline: 4.8014x; 1.1146x over previous
//
#include <hip/hip_runtime.h>
#include <hip/hip_bf16.h>

#define HW 9216
#define NPIX 18432

typedef __attribute__((ext_vector_type(8))) short short8v;
typedef __attribute__((ext_vector_type(4))) float f32x4;

// ---------------- weight prep: bf16 + fuse-weight transpose to [o][tap][c] ----------------
__global__ void prep_k(const float* __restrict__ w_fuse, const float* __restrict__ w_reduce,
                       const float* __restrict__ w_v0, const float* __restrict__ w_v1,
                       __hip_bfloat16* __restrict__ wt_fuse, __hip_bfloat16* __restrict__ wr_b,
                       __hip_bfloat16* __restrict__ wv0_b, __hip_bfloat16* __restrict__ wv1_b) {
    int i = blockIdx.x * 256 + threadIdx.x;
    if (i < 110592) {
        int o = i / 1728, r = i - o * 1728, tap = r / 192, c = r - tap * 192;
        wt_fuse[i] = __float2bfloat16(w_fuse[o * 1728 + c * 9 + tap]);
    }
    if (i < 8192) wr_b[i] = __float2bfloat16(w_reduce[i]);
    if (i < 4096) { wv0_b[i] = __float2bfloat16(w_v0[i]); wv1_b[i] = __float2bfloat16(w_v1[i]); }
}

// ---------------- transpose NCHW -> bf16 channels-last; past also -> featp + past_b ----------------
__global__ void transpose_cl_k(const float* __restrict__ past,
                               const float* __restrict__ curr,
                               __hip_bfloat16* __restrict__ curr_b,
                               __hip_bfloat16* __restrict__ featp,
                               __hip_bfloat16* __restrict__ past_b) {
    __shared__ float tile[32][33];
    int t = blockIdx.z & 1, b = blockIdx.z >> 1;
    const float* src = t ? curr : past;
    int p0 = blockIdx.x * 32, c0 = blockIdx.y * 32;
    for (int k = threadIdx.y; k < 32; k += 8)
        tile[k][threadIdx.x] = src[(size_t)(b * 64 + c0 + k) * HW + p0 + threadIdx.x];
    __syncthreads();
    for (int k = threadIdx.y; k < 32; k += 8) {
        __hip_bfloat16 hv = __float2bfloat16(tile[threadIdx.x][k]);
        int pp = p0 + k;
        if (t) {
            curr_b[((size_t)b * HW + pp) * 64 + c0 + threadIdx.x] = hv;
        } else {
            int y = pp / 96, x = pp - (pp / 96) * 96;
            featp[(((size_t)b * 98 + y + 1) * 98 + x + 1) * 192 + c0 + threadIdx.x] = hv;
            past_b[((size_t)b * HW + pp) * 64 + c0 + threadIdx.x] = hv;
        }
    }
}

// ---------------- shift + grouped 3x3 smooth conv: lane=pixel, wave=group ----------------
__global__ __launch_bounds__(512) void smooth_k(const float* __restrict__ past,
                                                const float* __restrict__ w_smooth,
                                                const float* __restrict__ b_smooth,
                                                __hip_bfloat16* __restrict__ smooth_b) {
    int g = threadIdx.x >> 6;
    int lane = threadIdx.x & 63;
    int p = blockIdx.x * 64 + lane;
    int b = p / HW, rem = p - b * HW;
    int y = rem / 96, x = rem - y * 96;
    int gi = g < 4 ? g : g + 1;
    int sy = gi / 3 - 1, sx = gi % 3 - 1;
    const float* base = past + (size_t)(b * 64 + g * 8) * HW;

    float v[9][8];
    #pragma unroll
    for (int ky = 0; ky < 3; ++ky) {
        #pragma unroll
        for (int kx = 0; kx < 3; ++kx) {
            int yy = y + ky - 1, xx = x + kx - 1;
            int ys = yy - sy, xs = xx - sx;
            bool ok = (unsigned)yy < 96u && (unsigned)xx < 96u &&
                      (unsigned)ys < 96u && (unsigned)xs < 96u;
            int off = ok ? (ys * 96 + xs) : rem;
            #pragma unroll
            for (int c = 0; c < 8; ++c) {
                float tv = base[(size_t)c * HW + off];
                v[ky * 3 + kx][c] = ok ? tv : 0.f;
            }
        }
    }
    float acc[8];
    #pragma unroll
    for (int j = 0; j < 8; ++j) acc[j] = b_smooth[g * 8 + j];
    #pragma unroll
    for (int j = 0; j < 8; ++j) {
        const float* wp = w_smooth + (g * 8 + j) * 72;
        #pragma unroll
        for (int c = 0; c < 8; ++c)
            #pragma unroll
            for (int t = 0; t < 9; ++t)
                acc[j] += wp[c * 9 + t] * v[t][c];
    }
    short8v pack;
    #pragma unroll
    for (int j = 0; j < 8; ++j) {
        __hip_bfloat16 h = __float2bfloat16(acc[j]);
        pack[j] = *reinterpret_cast<short*>(&h);
    }
    *reinterpret_cast<short8v*>(smooth_b + (size_t)p * 64 + g * 8) = pack;
}

// ---------------- MFMA 1x1 reduce: [past_b|smooth_b] (K=128) x wr_b -> past2_b ----------------
__global__ void reduce_mfma_k(const __hip_bfloat16* __restrict__ past_b,
                              const __hip_bfloat16* __restrict__ smooth_b,
                              const __hip_bfloat16* __restrict__ wr_b,
                              const float* __restrict__ b_reduce,
                              __hip_bfloat16* __restrict__ past2_b) {
    int p0 = blockIdx.x * 32;
    int tid = threadIdx.x, l = tid & 63, w = tid >> 6;
    int mtile = w >> 1, nbase = (w & 1) * 32;
    int lm = l & 15, g = l >> 4;
    f32x4 acc0 = {0, 0, 0, 0}, acc1 = {0, 0, 0, 0};
    size_t arow = (size_t)(p0 + mtile * 16 + lm) * 64 + g * 8;
    const __hip_bfloat16* b0p = wr_b + (size_t)(nbase + lm) * 128 + g * 8;
    const __hip_bfloat16* b1p = b0p + 16 * 128;
    #pragma unroll
    for (int c0 = 0; c0 < 128; c0 += 32) {
        const __hip_bfloat16* asrc = (c0 < 64) ? (past_b + arow + c0) : (smooth_b + arow + (c0 - 64));
        short8v a  = *reinterpret_cast<const short8v*>(asrc);
        short8v b0 = *reinterpret_cast<const short8v*>(b0p + c0);
        short8v b1 = *reinterpret_cast<const short8v*>(b1p + c0);
        acc0 = __builtin_amdgcn_mfma_f32_16x16x32_bf16(a, b0, acc0, 0, 0, 0);
        acc1 = __builtin_amdgcn_mfma_f32_16x16x32_bf16(a, b1, acc1, 0, 0, 0);
    }
    int o0 = nbase + lm, o1 = o0 + 16;
    float bias0 = b_reduce[o0], bias1 = b_reduce[o1];
    #pragma unroll
    for (int r = 0; r < 4; ++r) {
        int p = p0 + mtile * 16 + g * 4 + r;
        past2_b[(size_t)p * 64 + o0] = __float2bfloat16(acc0[r] + bias0);
        past2_b[(size_t)p * 64 + o1] = __float2bfloat16(acc1[r] + bias1);
    }
}

// ---------------- MFMA both V 1x1 convs -> bf16 ----------------
__global__ void vv_mfma_k(const __hip_bfloat16* __restrict__ past2_b,
                          const __hip_bfloat16* __restrict__ wv0_b,
                          const __hip_bfloat16* __restrict__ wv1_b,
                          const float* __restrict__ b_v0, const float* __restrict__ b_v1,
                          __hip_bfloat16* __restrict__ v0_b, __hip_bfloat16* __restrict__ v1_b) {
    int p0 = blockIdx.x * 32;
    int tid = threadIdx.x, l = tid & 63, w = tid >> 6;
    int mtile = w >> 1, nbase = (w & 1) * 32;
    int lm = l & 15, g = l >> 4;
    f32x4 acc00 = {0,0,0,0}, acc01 = {0,0,0,0}, acc10 = {0,0,0,0}, acc11 = {0,0,0,0};
    const __hip_bfloat16* ap = past2_b + (size_t)(p0 + mtile * 16 + lm) * 64 + g * 8;
    size_t bo = (size_t)(nbase + lm) * 64 + g * 8;
    #pragma unroll
    for (int c0 = 0; c0 < 64; c0 += 32) {
        short8v a   = *reinterpret_cast<const short8v*>(ap + c0);
        short8v b00 = *reinterpret_cast<const short8v*>(wv0_b + bo + c0);
        short8v b01 = *reinterpret_cast<const short8v*>(wv0_b + bo + 16 * 64 + c0);
        short8v b10 = *reinterpret_cast<const short8v*>(wv1_b + bo + c0);
        short8v b11 = *reinterpret_cast<const short8v*>(wv1_b + bo + 16 * 64 + c0);
        acc00 = __builtin_amdgcn_mfma_f32_16x16x32_bf16(a, b00, acc00, 0, 0, 0);
        acc01 = __builtin_amdgcn_mfma_f32_16x16x32_bf16(a, b01, acc01, 0, 0, 0);
        acc10 = __builtin_amdgcn_mfma_f32_16x16x32_bf16(a, b10, acc10, 0, 0, 0);
        acc11 = __builtin_amdgcn_mfma_f32_16x16x32_bf16(a, b11, acc11, 0, 0, 0);
    }
    int o0 = nbase + lm, o1 = o0 + 16;
    float bi00 = b_v0[o0], bi01 = b_v0[o1], bi10 = b_v1[o0], bi11 = b_v1[o1];
    #pragma unroll
    for (int r = 0; r < 4; ++r) {
        int p = p0 + mtile * 16 + g * 4 + r;
        v0_b[(size_t)p * 64 + o0] = __float2bfloat16(acc00[r] + bi00);
        v0_b[(size_t)p * 64 + o1] = __float2bfloat16(acc01[r] + bi01);
        v1_b[(size_t)p * 64 + o0] = __float2bfloat16(acc10[r] + bi10);
        v1_b[(size_t)p * 64 + o1] = __float2bfloat16(acc11[r] + bi11);
    }
}

// ---------------- MFMA neighborhood attention: 16-pixel row strip per block ----------------
template <int KS>
__global__ __launch_bounds__(256) void natten_mfma_k(
    const __hip_bfloat16* __restrict__ q_b,
    const __hip_bfloat16* __restrict__ k_b,
    const __hip_bfloat16* __restrict__ v_b,
    const float* __restrict__ rpb,
    __hip_bfloat16* __restrict__ featp, int coff) {
    constexpr int R = KS / 2, RW = 2 * KS - 1;
    constexpr int CW = 16 + KS - 1;            // union col width
    constexpr int NPOS = KS * CW;              // 154 / 54
    constexpr int NPAD = (NPOS + 31) & ~31;    // 160 / 64
    constexpr int NT = NPAD / 16;              // QK n-tiles: 10 / 4
    constexpr int KROW = 72;                   // K_lds row (u16), pad -> 2-way max
    constexpr int VROW = NPAD + 8;             // Vt row (u16)
    constexpr int PROW = NPAD + 8;             // P row (u16)
    constexpr int SROW = NPAD + 1;             // S row (f32), overlays K

    __shared__ __align__(16) char smem[16 * 72 * 2 + NPAD * KROW * 2 + 64 * VROW * 2 +
                                       16 * PROW * 2 + RW * RW * 4];
    __hip_bfloat16* Q  = (__hip_bfloat16*)smem;
    __hip_bfloat16* K  = (__hip_bfloat16*)(smem + 16 * 72 * 2);
    float*          S  = (float*)K;            // overlay after QK MFMAs complete
    __hip_bfloat16* Vt = (__hip_bfloat16*)(smem + 16 * 72 * 2 + NPAD * KROW * 2);
    __hip_bfloat16* P  = (__hip_bfloat16*)((char*)Vt + 64 * VROW * 2);
    float*       rpb_s = (float*)((char*)P + 16 * PROW * 2);

    int blk = blockIdx.x;
    int x0 = (blk % 6) * 16;
    int row = blk / 6;
    int b = row / 96, y = row - b * 96;
    int y0 = y - R;  y0 = y0 < 0 ? 0 : (y0 > 96 - KS ? 96 - KS : y0);
    int c0 = x0 - R; c0 = c0 < 0 ? 0 : (c0 > 96 - KS ? 96 - KS : c0);
    int tid = threadIdx.x;
    size_t plane = (size_t)b * HW;

    // ---- stage Q + rpb ----
    if (tid < 128) {
        int px = tid >> 3, c8 = (tid & 7) * 8;
        *(short8v*)(Q + px * 72 + c8) =
            *(const short8v*)(q_b + (plane + y * 96 + x0 + px) * 64 + c8);
    } else {
        for (int i = tid - 128; i < RW * RW; i += 128) rpb_s[i] = rpb[i];
    }
    // ---- stage K union (zero rows for pos >= NPOS) ----
    for (int pos = tid >> 3; pos < NPAD; pos += 32) {
        int c8 = (tid & 7) * 8;
        short8v val = {0, 0, 0, 0, 0, 0, 0, 0};
        if (pos < NPOS) {
            int i = pos / CW, jc = pos - i * CW;
            int gy = y0 + i;
            int gx = c0 + jc; gx = gx > 95 ? 95 : gx;   // OOB cols masked later
            val = *(const short8v*)(k_b + (plane + gy * 96 + gx) * 64 + c8);
        }
        *(short8v*)(K + pos * KROW + c8) = val;
    }
    // ---- stage V transposed ----
    for (int pos = tid >> 6; pos < NPAD; pos += 4) {
        int c = tid & 63;
        __hip_bfloat16 val = __float2bfloat16(0.f);
        if (pos < NPOS) {
            int i = pos / CW, jc = pos - i * CW;
            int gy = y0 + i;
            int gx = c0 + jc; gx = gx > 95 ? 95 : gx;
            val = v_b[(plane + gy * 96 + gx) * 64 + c];
        }
        Vt[c * VROW + pos] = val;
    }
    __syncthreads();

    int l = tid & 63, w = tid >> 6;
    int lm = l & 15, g = l >> 4;

    // ---- QK^T: wave w handles n-tiles w, w+4, w+8 (static indexing) ----
    short8v qa0 = *(const short8v*)(Q + lm * 72 + g * 8);
    short8v qa1 = *(const short8v*)(Q + lm * 72 + g * 8 + 32);
    f32x4 sacc[3];
    #pragma unroll
    for (int k = 0; k < 3; ++k) {
        int t = w + 4 * k;
        if (t < NT) {
            f32x4 acc = {0, 0, 0, 0};
            const __hip_bfloat16* kp = K + (t * 16 + lm) * KROW + g * 8;
            acc = __builtin_amdgcn_mfma_f32_16x16x32_bf16(qa0, *(const short8v*)kp, acc, 0, 0, 0);
            acc = __builtin_amdgcn_mfma_f32_16x16x32_bf16(qa1, *(const short8v*)(kp + 32), acc, 0, 0, 0);
            sacc[k] = acc;
        }
    }
    __syncthreads();   // all K reads done; S may overwrite K

    // ---- bias + mask -> S ----
    #pragma unroll
    for (int k = 0; k < 3; ++k) {
        int t = w + 4 * k;
        if (t < NT) {
            int pos = t * 16 + lm;
            int i = pos / CW, jc = pos - i * CW;
            int ac = c0 + jc;
            int rel_h = y0 + i - y + KS - 1;
            #pragma unroll
            for (int r = 0; r < 4; ++r) {
                int px = g * 4 + r;
                int x = x0 + px;
                int xw = x - R; xw = xw < 0 ? 0 : (xw > 96 - KS ? 96 - KS : xw);
                int d = ac - xw;
                float sv = -1e30f;
                if (pos < NPOS && (unsigned)d < (unsigned)KS)
                    sv = sacc[k][r] + rpb_s[rel_h * RW + (ac - x + KS - 1)];
                S[px * SROW + pos] = sv;
            }
        }
    }
    __syncthreads();

    // ---- softmax: wave w -> pixels 4w+g; 16 workers (lm) per pixel ----
    {
        int px = 4 * w + g;
        float vals[NT];
        float m = -1e30f;
        #pragma unroll
        for (int k = 0; k < NT; ++k) {
            vals[k] = S[px * SROW + lm + 16 * k];
            m = fmaxf(m, vals[k]);
        }
        #pragma unroll
        for (int off = 1; off < 16; off <<= 1) m = fmaxf(m, __shfl_xor(m, off));
        float sum = 0.f;
        #pragma unroll
        for (int k = 0; k < NT; ++k) { vals[k] = __expf(vals[k] - m); sum += vals[k]; }
        #pragma unroll
        for (int off = 1; off < 16; off <<= 1) sum += __shfl_xor(sum, off);
        float rs = 1.f / sum;
        #pragma unroll
        for (int k = 0; k < NT; ++k)
            P[px * PROW + lm + 16 * k] = __float2bfloat16(vals[k] * rs);
    }
    __syncthreads();

    // ---- PV: wave w -> output channels [16w, 16w+16) ----
    f32x4 oacc = {0, 0, 0, 0};
    #pragma unroll
    for (int kk = 0; kk < NPAD / 32; ++kk) {
        short8v pa = *(const short8v*)(P + lm * PROW + kk * 32 + g * 8);
        short8v vb = *(const short8v*)(Vt + (w * 16 + lm) * VROW + kk * 32 + g * 8);
        oacc = __builtin_amdgcn_mfma_f32_16x16x32_bf16(pa, vb, oacc, 0, 0, 0);
    }
    __hip_bfloat16* ob = featp + (((size_t)b * 98 + y + 1) * 98 + (x0 + 1)) * 192 + coff + w * 16 + lm;
    #pragma unroll
    for (int r = 0; r < 4; ++r) {
        int px = g * 4 + r;
        ob[(size_t)px * 192] = __float2bfloat16(oacc[r]);
    }
}

// ---------------- fuse conv v3: split-K across waves, LDS reduce, NCHW out ----------------
// Block: 32 pixels x 64 out-ch. Wave w owns k-steps [KSB[w], KSB[w+1]) of 54 (k-step=32).
__global__ __launch_bounds__(256) void fuse_v3_k(const __hip_bfloat16* __restrict__ featp,
                                                 const __hip_bfloat16* __restrict__ wt,
                                                 const float* __restrict__ b_fuse,
                                                 float* __restrict__ out) {
    __shared__ f32x4 red[4 * 2 * 4 * 64];   // [wave][mt][nt][lane] = 32 KB
    int tid = threadIdx.x;
    int l = tid & 63, w = tid >> 6;
    int lm = l & 15, g = l >> 4;
    int p0 = blockIdx.x * 32;               // 32 | 9216: never crosses batch
    int b = p0 / HW, rem0 = p0 - b * HW;

    const __hip_bfloat16* baseA[2];
    #pragma unroll
    for (int mt = 0; mt < 2; ++mt) {
        int rem = rem0 + mt * 16 + lm;
        int y = rem / 96, x = rem - y * 96;
        baseA[mt] = featp + (((size_t)b * 98 + y) * 98 + x) * 192 + g * 8;
    }
    const __hip_bfloat16* baseB = wt + (size_t)lm * 1728 + g * 8;

    const int KSB[5] = {0, 13, 27, 40, 54};
    int ks_b = KSB[w], ks_e = KSB[w + 1];

    f32x4 acc[2][4] = {};
    for (int ks = ks_b; ks < ks_e; ++ks) {
        int tap = ks / 6;                         // 6 k-steps per tap (192/32)
        int c0 = (ks - tap * 6) * 32;
        int aoff = ((tap / 3) * 98 + (tap % 3)) * 192 + c0;   // (dy+1, dx+1) row offset
        short8v a0 = *(const short8v*)(baseA[0] + aoff);
        short8v a1 = *(const short8v*)(baseA[1] + aoff);
        int boff = ks * 32;
        short8v b0 = *(const short8v*)(baseB + 0 * 16 * 1728 + boff);
        short8v b1 = *(const short8v*)(baseB + 1 * 16 * 1728 + boff);
        short8v b2 = *(const short8v*)(baseB + 2 * 16 * 1728 + boff);
        short8v b3 = *(const short8v*)(baseB + 3 * 16 * 1728 + boff);
        acc[0][0] = __builtin_amdgcn_mfma_f32_16x16x32_bf16(a0, b0, acc[0][0], 0, 0, 0);
        acc[0][1] = __builtin_amdgcn_mfma_f32_16x16x32_bf16(a0, b1, acc[0][1], 0, 0, 0);
        acc[0][2] = __builtin_amdgcn_mfma_f32_16x16x32_bf16(a0, b2, acc[0][2], 0, 0, 0);
        acc[0][3] = __builtin_amdgcn_mfma_f32_16x16x32_bf16(a0, b3, acc[0][3], 0, 0, 0);
        acc[1][0] = __builtin_amdgcn_mfma_f32_16x16x32_bf16(a1, b0, acc[1][0], 0, 0, 0);
        acc[1][1] = __builtin_amdgcn_mfma_f32_16x16x32_bf16(a1, b1, acc[1][1], 0, 0, 0);
        acc[1][2] = __builtin_amdgcn_mfma_f32_16x16x32_bf16(a1, b2, acc[1][2], 0, 0, 0);
        acc[1][3] = __builtin_amdgcn_mfma_f32_16x16x32_bf16(a1, b3, acc[1][3], 0, 0, 0);
    }

    #pragma unroll
    for (int mt = 0; mt < 2; ++mt)
        #pragma unroll
        for (int nt = 0; nt < 4; ++nt)
            red[((w * 2 + mt) * 4 + nt) * 64 + l] = acc[mt][nt];
    __syncthreads();

    // each thread produces 8 output elems: o = tid>>2, px = (tid&3)*8 + i
    #pragma unroll
    for (int i = 0; i < 8; ++i) {
        int e = tid * 8 + i;
        int o = e >> 5, px = e & 31;
        int mt = px >> 4, gg = (px >> 2) & 3, r = px & 3;
        int lane = gg * 16 + (o & 15), nt = o >> 4;
        float s = b_fuse[o];
        #pragma unroll
        for (int ww = 0; ww < 4; ++ww)
            s += red[((ww * 2 + mt) * 4 + nt) * 64 + lane][r];
        out[(size_t)(b * 64 + o) * HW + rem0 + px] = s;
    }
}

extern "C" void kernel_launch(void* const* d_in, const int* in_sizes, int n_in,
                              void* d_out, int out_size, void* d_ws, size_t ws_size,
                              hipStream_t stream) {
    const float* past     = (const float*)d_in[0];
    const float* curr     = (const float*)d_in[1];
    const float* w_smooth = (const float*)d_in[2];
    const float* b_smooth = (const float*)d_in[3];
    const float* w_reduce = (const float*)d_in[4];
    const float* b_reduce = (const float*)d_in[5];
    const float* w_v0     = (const float*)d_in[6];
    const float* b_v0     = (const float*)d_in[7];
    const float* w_v1     = (const float*)d_in[8];
    const float* b_v1     = (const float*)d_in[9];
    const float* rpb0     = (const float*)d_in[10];
    const float* rpb1     = (const float*)d_in[11];
    const float* w_fuse   = (const float*)d_in[12];
    const float* b_fuse   = (const float*)d_in[13];
    float* out = (float*)d_out;

    const size_t NF = (size_t)NPIX * 64;
    char* p = (char*)d_ws;
    auto carve = [&](size_t bytes) { char* r = p; p += (bytes + 255) & ~(size_t)255; return r; };
    __hip_bfloat16* featp    = (__hip_bfloat16*)carve((size_t)2 * 98 * 98 * 192 * 2);
    __hip_bfloat16* curr_b   = (__hip_bfloat16*)carve(NF * 2);
    __hip_bfloat16* past_b   = (__hip_bfloat16*)carve(NF * 2);
    __hip_bfloat16* smooth_b = (__hip_bfloat16*)carve(NF * 2);
    __hip_bfloat16* past2_b  = (__hip_bfloat16*)carve(NF * 2);
    __hip_bfloat16* v0_b     = (__hip_bfloat16*)carve(NF * 2);
    __hip_bfloat16* v1_b     = (__hip_bfloat16*)carve(NF * 2);
    __hip_bfloat16* wt_fuse  = (__hip_bfloat16*)carve((size_t)64 * 1728 * 2);
    __hip_bfloat16* wr_b     = (__hip_bfloat16*)carve((size_t)64 * 128 * 2);
    __hip_bfloat16* wv0_b    = (__hip_bfloat16*)carve((size_t)64 * 64 * 2);
    __hip_bfloat16* wv1_b    = (__hip_bfloat16*)carve((size_t)64 * 64 * 2);

    hipMemsetAsync(featp, 0, (size_t)2 * 98 * 98 * 192 * 2, stream);
    prep_k<<<432, 256, 0, stream>>>(w_fuse, w_reduce, w_v0, w_v1, wt_fuse, wr_b, wv0_b, wv1_b);

    dim3 tb(32, 8, 1), tg(HW / 32, 2, 4);
    transpose_cl_k<<<tg, tb, 0, stream>>>(past, curr, curr_b, featp, past_b);
    smooth_k<<<NPIX / 64, 512, 0, stream>>>(past, w_smooth, b_smooth, smooth_b);
    reduce_mfma_k<<<NPIX / 32, 256, 0, stream>>>(past_b, smooth_b, wr_b, b_reduce, past2_b);
    vv_mfma_k<<<NPIX / 32, 256, 0, stream>>>(past2_b, wv0_b, wv1_b, b_v0, b_v1, v0_b, v1_b);
    natten_mfma_k<3><<<NPIX / 16, 256, 0, stream>>>(curr_b, past2_b, v0_b, rpb0, featp, 64);
    natten_mfma_k<7><<<NPIX / 16, 256, 0, stream>>>(curr_b, past2_b, v1_b, rpb1, featp, 128);
    fuse_v3_k<<<NPIX / 32, 256, 0, stream>>>(featp, wt_fuse, b_fuse, out);
}

// Round 7
// 134.626 us; speedup vs baseline: 5.3396x; 1.1121x over previous
//
#include <hip/hip_runtime.h>
#include <hip/hip_bf16.h>

#define HW 9216
#define NPIX 18432

typedef __attribute__((ext_vector_type(8))) short short8v;
typedef __attribute__((ext_vector_type(4))) float f32x4;

__device__ __forceinline__ float bf2f(short s) {
    union { unsigned u; float f; } c;
    c.u = ((unsigned)(unsigned short)s) << 16;
    return c.f;
}

// ---------------- weight prep: bf16 + fuse-weight transpose to [o][tap][c] ----------------
__global__ void prep_k(const float* __restrict__ w_fuse, const float* __restrict__ w_reduce,
                       const float* __restrict__ w_v0, const float* __restrict__ w_v1,
                       __hip_bfloat16* __restrict__ wt_fuse, __hip_bfloat16* __restrict__ wr_b,
                       __hip_bfloat16* __restrict__ wv0_b, __hip_bfloat16* __restrict__ wv1_b) {
    int i = blockIdx.x * 256 + threadIdx.x;
    if (i < 110592) {
        int o = i / 1728, r = i - o * 1728, tap = r / 192, c = r - tap * 192;
        wt_fuse[i] = __float2bfloat16(w_fuse[o * 1728 + c * 9 + tap]);
    }
    if (i < 8192) wr_b[i] = __float2bfloat16(w_reduce[i]);
    if (i < 4096) { wv0_b[i] = __float2bfloat16(w_v0[i]); wv1_b[i] = __float2bfloat16(w_v1[i]); }
}

// ---------------- zero only featp's 1-pixel border ring ----------------
__global__ void zero_border_k(__hip_bfloat16* __restrict__ featp) {
    int i = blockIdx.x * 256 + threadIdx.x;      // over 2*98*98 padded pixels
    if (i >= 2 * 98 * 98) return;
    int pp = i % (98 * 98);
    int y = pp / 98, x = pp - y * 98;
    if (y == 0 || y == 97 || x == 0 || x == 97) {
        short8v z = {0, 0, 0, 0, 0, 0, 0, 0};
        short8v* d = (short8v*)(featp + (size_t)i * 192);
        #pragma unroll
        for (int k = 0; k < 24; ++k) d[k] = z;
    }
}

// ---------------- transpose NCHW -> bf16 channels-last; past also -> featp + past_b ----------------
__global__ void transpose_cl_k(const float* __restrict__ past,
                               const float* __restrict__ curr,
                               __hip_bfloat16* __restrict__ curr_b,
                               __hip_bfloat16* __restrict__ featp,
                               __hip_bfloat16* __restrict__ past_b) {
    __shared__ float tile[32][33];
    int t = blockIdx.z & 1, b = blockIdx.z >> 1;
    const float* src = t ? curr : past;
    int p0 = blockIdx.x * 32, c0 = blockIdx.y * 32;
    for (int k = threadIdx.y; k < 32; k += 8)
        tile[k][threadIdx.x] = src[(size_t)(b * 64 + c0 + k) * HW + p0 + threadIdx.x];
    __syncthreads();
    for (int k = threadIdx.y; k < 32; k += 8) {
        __hip_bfloat16 hv = __float2bfloat16(tile[threadIdx.x][k]);
        int pp = p0 + k;
        if (t) {
            curr_b[((size_t)b * HW + pp) * 64 + c0 + threadIdx.x] = hv;
        } else {
            int y = pp / 96, x = pp - (pp / 96) * 96;
            featp[(((size_t)b * 98 + y + 1) * 98 + x + 1) * 192 + c0 + threadIdx.x] = hv;
            past_b[((size_t)b * HW + pp) * 64 + c0 + threadIdx.x] = hv;
        }
    }
}

// ---------------- shift + grouped 3x3 smooth conv: lane=pixel, wave=group, bf16x8 taps ----------------
__global__ __launch_bounds__(512) void smooth_k(const __hip_bfloat16* __restrict__ past_b,
                                                const float* __restrict__ w_smooth,
                                                const float* __restrict__ b_smooth,
                                                __hip_bfloat16* __restrict__ smooth_b) {
    int g = threadIdx.x >> 6;                 // wave = group (uniform sy,sx)
    int lane = threadIdx.x & 63;
    int p = blockIdx.x * 64 + lane;           // 64 | 9216: never crosses batch
    int b = p / HW, rem = p - b * HW;
    int y = rem / 96, x = rem - y * 96;
    int gi = g < 4 ? g : g + 1;               // skip (0,0)
    int sy = gi / 3 - 1, sx = gi % 3 - 1;
    const __hip_bfloat16* base = past_b + (size_t)b * HW * 64 + g * 8;

    float v[9][8];
    #pragma unroll
    for (int ky = 0; ky < 3; ++ky) {
        #pragma unroll
        for (int kx = 0; kx < 3; ++kx) {
            int yy = y + ky - 1, xx = x + kx - 1;      // conv zero-pad bounds
            int ys = yy - sy, xs = xx - sx;            // shifted-in-zero bounds
            bool ok = (unsigned)yy < 96u && (unsigned)xx < 96u &&
                      (unsigned)ys < 96u && (unsigned)xs < 96u;
            int off = ok ? (ys * 96 + xs) : rem;       // clamped, in-bounds
            short8v ld = *(const short8v*)(base + (size_t)off * 64);
            float okf = ok ? 1.f : 0.f;
            #pragma unroll
            for (int c = 0; c < 8; ++c)
                v[ky * 3 + kx][c] = okf * bf2f(ld[c]);
        }
    }
    float acc[8];
    #pragma unroll
    for (int j = 0; j < 8; ++j) acc[j] = b_smooth[g * 8 + j];
    #pragma unroll
    for (int j = 0; j < 8; ++j) {
        const float* wp = w_smooth + (g * 8 + j) * 72;   // wave-uniform -> s_load
        #pragma unroll
        for (int c = 0; c < 8; ++c)
            #pragma unroll
            for (int t = 0; t < 9; ++t)
                acc[j] += wp[c * 9 + t] * v[t][c];
    }
    short8v pack;
    #pragma unroll
    for (int j = 0; j < 8; ++j) {
        __hip_bfloat16 h = __float2bfloat16(acc[j]);
        pack[j] = *reinterpret_cast<short*>(&h);
    }
    *reinterpret_cast<short8v*>(smooth_b + (size_t)p * 64 + g * 8) = pack;
}

// ---------------- MFMA 1x1 reduce: [past_b|smooth_b] (K=128) x wr_b -> past2_b ----------------
__global__ void reduce_mfma_k(const __hip_bfloat16* __restrict__ past_b,
                              const __hip_bfloat16* __restrict__ smooth_b,
                              const __hip_bfloat16* __restrict__ wr_b,
                              const float* __restrict__ b_reduce,
                              __hip_bfloat16* __restrict__ past2_b) {
    int p0 = blockIdx.x * 32;
    int tid = threadIdx.x, l = tid & 63, w = tid >> 6;
    int mtile = w >> 1, nbase = (w & 1) * 32;
    int lm = l & 15, g = l >> 4;
    f32x4 acc0 = {0, 0, 0, 0}, acc1 = {0, 0, 0, 0};
    size_t arow = (size_t)(p0 + mtile * 16 + lm) * 64 + g * 8;
    const __hip_bfloat16* b0p = wr_b + (size_t)(nbase + lm) * 128 + g * 8;
    const __hip_bfloat16* b1p = b0p + 16 * 128;
    #pragma unroll
    for (int c0 = 0; c0 < 128; c0 += 32) {
        const __hip_bfloat16* asrc = (c0 < 64) ? (past_b + arow + c0) : (smooth_b + arow + (c0 - 64));
        short8v a  = *reinterpret_cast<const short8v*>(asrc);
        short8v b0 = *reinterpret_cast<const short8v*>(b0p + c0);
        short8v b1 = *reinterpret_cast<const short8v*>(b1p + c0);
        acc0 = __builtin_amdgcn_mfma_f32_16x16x32_bf16(a, b0, acc0, 0, 0, 0);
        acc1 = __builtin_amdgcn_mfma_f32_16x16x32_bf16(a, b1, acc1, 0, 0, 0);
    }
    int o0 = nbase + lm, o1 = o0 + 16;
    float bias0 = b_reduce[o0], bias1 = b_reduce[o1];
    #pragma unroll
    for (int r = 0; r < 4; ++r) {
        int p = p0 + mtile * 16 + g * 4 + r;
        past2_b[(size_t)p * 64 + o0] = __float2bfloat16(acc0[r] + bias0);
        past2_b[(size_t)p * 64 + o1] = __float2bfloat16(acc1[r] + bias1);
    }
}

// ---------------- MFMA both V 1x1 convs -> bf16 ----------------
__global__ void vv_mfma_k(const __hip_bfloat16* __restrict__ past2_b,
                          const __hip_bfloat16* __restrict__ wv0_b,
                          const __hip_bfloat16* __restrict__ wv1_b,
                          const float* __restrict__ b_v0, const float* __restrict__ b_v1,
                          __hip_bfloat16* __restrict__ v0_b, __hip_bfloat16* __restrict__ v1_b) {
    int p0 = blockIdx.x * 32;
    int tid = threadIdx.x, l = tid & 63, w = tid >> 6;
    int mtile = w >> 1, nbase = (w & 1) * 32;
    int lm = l & 15, g = l >> 4;
    f32x4 acc00 = {0,0,0,0}, acc01 = {0,0,0,0}, acc10 = {0,0,0,0}, acc11 = {0,0,0,0};
    const __hip_bfloat16* ap = past2_b + (size_t)(p0 + mtile * 16 + lm) * 64 + g * 8;
    size_t bo = (size_t)(nbase + lm) * 64 + g * 8;
    #pragma unroll
    for (int c0 = 0; c0 < 64; c0 += 32) {
        short8v a   = *reinterpret_cast<const short8v*>(ap + c0);
        short8v b00 = *reinterpret_cast<const short8v*>(wv0_b + bo + c0);
        short8v b01 = *reinterpret_cast<const short8v*>(wv0_b + bo + 16 * 64 + c0);
        short8v b10 = *reinterpret_cast<const short8v*>(wv1_b + bo + c0);
        short8v b11 = *reinterpret_cast<const short8v*>(wv1_b + bo + 16 * 64 + c0);
        acc00 = __builtin_amdgcn_mfma_f32_16x16x32_bf16(a, b00, acc00, 0, 0, 0);
        acc01 = __builtin_amdgcn_mfma_f32_16x16x32_bf16(a, b01, acc01, 0, 0, 0);
        acc10 = __builtin_amdgcn_mfma_f32_16x16x32_bf16(a, b10, acc10, 0, 0, 0);
        acc11 = __builtin_amdgcn_mfma_f32_16x16x32_bf16(a, b11, acc11, 0, 0, 0);
    }
    int o0 = nbase + lm, o1 = o0 + 16;
    float bi00 = b_v0[o0], bi01 = b_v0[o1], bi10 = b_v1[o0], bi11 = b_v1[o1];
    #pragma unroll
    for (int r = 0; r < 4; ++r) {
        int p = p0 + mtile * 16 + g * 4 + r;
        v0_b[(size_t)p * 64 + o0] = __float2bfloat16(acc00[r] + bi00);
        v0_b[(size_t)p * 64 + o1] = __float2bfloat16(acc01[r] + bi01);
        v1_b[(size_t)p * 64 + o0] = __float2bfloat16(acc10[r] + bi10);
        v1_b[(size_t)p * 64 + o1] = __float2bfloat16(acc11[r] + bi11);
    }
}

// ---------------- MFMA neighborhood attention: 16-pixel row strip per block ----------------
template <int KS>
__global__ __launch_bounds__(256) void natten_mfma_k(
    const __hip_bfloat16* __restrict__ q_b,
    const __hip_bfloat16* __restrict__ k_b,
    const __hip_bfloat16* __restrict__ v_b,
    const float* __restrict__ rpb,
    __hip_bfloat16* __restrict__ featp, int coff) {
    constexpr int R = KS / 2, RW = 2 * KS - 1;
    constexpr int CW = 16 + KS - 1;            // union col width
    constexpr int NPOS = KS * CW;              // 154 / 54
    constexpr int NPAD = (NPOS + 31) & ~31;    // 160 / 64
    constexpr int NT = NPAD / 16;              // QK n-tiles: 10 / 4
    constexpr int KROW = 72;                   // K_lds row (u16), pad -> 2-way max
    constexpr int VROW = NPAD + 8;             // Vt row (u16)
    constexpr int PROW = NPAD + 8;             // P row (u16)
    constexpr int SROW = NPAD + 1;             // S row (f32), overlays K

    __shared__ __align__(16) char smem[16 * 72 * 2 + NPAD * KROW * 2 + 64 * VROW * 2 +
                                       16 * PROW * 2 + RW * RW * 4];
    __hip_bfloat16* Q  = (__hip_bfloat16*)smem;
    __hip_bfloat16* K  = (__hip_bfloat16*)(smem + 16 * 72 * 2);
    float*          S  = (float*)K;            // overlay after QK MFMAs complete
    __hip_bfloat16* Vt = (__hip_bfloat16*)(smem + 16 * 72 * 2 + NPAD * KROW * 2);
    __hip_bfloat16* P  = (__hip_bfloat16*)((char*)Vt + 64 * VROW * 2);
    float*       rpb_s = (float*)((char*)P + 16 * PROW * 2);

    int blk = blockIdx.x;
    int x0 = (blk % 6) * 16;
    int row = blk / 6;
    int b = row / 96, y = row - b * 96;
    int y0 = y - R;  y0 = y0 < 0 ? 0 : (y0 > 96 - KS ? 96 - KS : y0);
    int c0 = x0 - R; c0 = c0 < 0 ? 0 : (c0 > 96 - KS ? 96 - KS : c0);
    int tid = threadIdx.x;
    size_t plane = (size_t)b * HW;

    // ---- stage Q + rpb ----
    if (tid < 128) {
        int px = tid >> 3, c8 = (tid & 7) * 8;
        *(short8v*)(Q + px * 72 + c8) =
            *(const short8v*)(q_b + (plane + y * 96 + x0 + px) * 64 + c8);
    } else {
        for (int i = tid - 128; i < RW * RW; i += 128) rpb_s[i] = rpb[i];
    }
    // ---- stage K union (zero rows for pos >= NPOS) ----
    for (int pos = tid >> 3; pos < NPAD; pos += 32) {
        int c8 = (tid & 7) * 8;
        short8v val = {0, 0, 0, 0, 0, 0, 0, 0};
        if (pos < NPOS) {
            int i = pos / CW, jc = pos - i * CW;
            int gy = y0 + i;
            int gx = c0 + jc; gx = gx > 95 ? 95 : gx;   // OOB cols masked later
            val = *(const short8v*)(k_b + (plane + gy * 96 + gx) * 64 + c8);
        }
        *(short8v*)(K + pos * KROW + c8) = val;
    }
    // ---- stage V transposed ----
    for (int pos = tid >> 6; pos < NPAD; pos += 4) {
        int c = tid & 63;
        __hip_bfloat16 val = __float2bfloat16(0.f);
        if (pos < NPOS) {
            int i = pos / CW, jc = pos - i * CW;
            int gy = y0 + i;
            int gx = c0 + jc; gx = gx > 95 ? 95 : gx;
            val = v_b[(plane + gy * 96 + gx) * 64 + c];
        }
        Vt[c * VROW + pos] = val;
    }
    __syncthreads();

    int l = tid & 63, w = tid >> 6;
    int lm = l & 15, g = l >> 4;

    // ---- QK^T: wave w handles n-tiles w, w+4, w+8 (static indexing) ----
    short8v qa0 = *(const short8v*)(Q + lm * 72 + g * 8);
    short8v qa1 = *(const short8v*)(Q + lm * 72 + g * 8 + 32);
    f32x4 sacc[3];
    #pragma unroll
    for (int k = 0; k < 3; ++k) {
        int t = w + 4 * k;
        if (t < NT) {
            f32x4 acc = {0, 0, 0, 0};
            const __hip_bfloat16* kp = K + (t * 16 + lm) * KROW + g * 8;
            acc = __builtin_amdgcn_mfma_f32_16x16x32_bf16(qa0, *(const short8v*)kp, acc, 0, 0, 0);
            acc = __builtin_amdgcn_mfma_f32_16x16x32_bf16(qa1, *(const short8v*)(kp + 32), acc, 0, 0, 0);
            sacc[k] = acc;
        }
    }
    __syncthreads();   // all K reads done; S may overwrite K

    // ---- bias + mask -> S ----
    #pragma unroll
    for (int k = 0; k < 3; ++k) {
        int t = w + 4 * k;
        if (t < NT) {
            int pos = t * 16 + lm;
            int i = pos / CW, jc = pos - i * CW;
            int ac = c0 + jc;
            int rel_h = y0 + i - y + KS - 1;
            #pragma unroll
            for (int r = 0; r < 4; ++r) {
                int px = g * 4 + r;
                int x = x0 + px;
                int xw = x - R; xw = xw < 0 ? 0 : (xw > 96 - KS ? 96 - KS : xw);
                int d = ac - xw;
                float sv = -1e30f;
                if (pos < NPOS && (unsigned)d < (unsigned)KS)
                    sv = sacc[k][r] + rpb_s[rel_h * RW + (ac - x + KS - 1)];
                S[px * SROW + pos] = sv;
            }
        }
    }
    __syncthreads();

    // ---- softmax: wave w -> pixels 4w+g; 16 workers (lm) per pixel ----
    {
        int px = 4 * w + g;
        float vals[NT];
        float m = -1e30f;
        #pragma unroll
        for (int k = 0; k < NT; ++k) {
            vals[k] = S[px * SROW + lm + 16 * k];
            m = fmaxf(m, vals[k]);
        }
        #pragma unroll
        for (int off = 1; off < 16; off <<= 1) m = fmaxf(m, __shfl_xor(m, off));
        float sum = 0.f;
        #pragma unroll
        for (int k = 0; k < NT; ++k) { vals[k] = __expf(vals[k] - m); sum += vals[k]; }
        #pragma unroll
        for (int off = 1; off < 16; off <<= 1) sum += __shfl_xor(sum, off);
        float rs = 1.f / sum;
        #pragma unroll
        for (int k = 0; k < NT; ++k)
            P[px * PROW + lm + 16 * k] = __float2bfloat16(vals[k] * rs);
    }
    __syncthreads();

    // ---- PV: wave w -> output channels [16w, 16w+16) ----
    f32x4 oacc = {0, 0, 0, 0};
    #pragma unroll
    for (int kk = 0; kk < NPAD / 32; ++kk) {
        short8v pa = *(const short8v*)(P + lm * PROW + kk * 32 + g * 8);
        short8v vb = *(const short8v*)(Vt + (w * 16 + lm) * VROW + kk * 32 + g * 8);
        oacc = __builtin_amdgcn_mfma_f32_16x16x32_bf16(pa, vb, oacc, 0, 0, 0);
    }
    __hip_bfloat16* ob = featp + (((size_t)b * 98 + y + 1) * 98 + (x0 + 1)) * 192 + coff + w * 16 + lm;
    #pragma unroll
    for (int r = 0; r < 4; ++r) {
        int px = g * 4 + r;
        ob[(size_t)px * 192] = __float2bfloat16(oacc[r]);
    }
}

// ---------------- fuse conv v3: split-K across waves, LDS reduce, NCHW out ----------------
__global__ __launch_bounds__(256) void fuse_v3_k(const __hip_bfloat16* __restrict__ featp,
                                                 const __hip_bfloat16* __restrict__ wt,
                                                 const float* __restrict__ b_fuse,
                                                 float* __restrict__ out) {
    __shared__ f32x4 red[4 * 2 * 4 * 64];   // [wave][mt][nt][lane] = 32 KB
    int tid = threadIdx.x;
    int l = tid & 63, w = tid >> 6;
    int lm = l & 15, g = l >> 4;
    int p0 = blockIdx.x * 32;               // 32 | 9216: never crosses batch
    int b = p0 / HW, rem0 = p0 - b * HW;

    const __hip_bfloat16* baseA[2];
    #pragma unroll
    for (int mt = 0; mt < 2; ++mt) {
        int rem = rem0 + mt * 16 + lm;
        int y = rem / 96, x = rem - y * 96;
        baseA[mt] = featp + (((size_t)b * 98 + y) * 98 + x) * 192 + g * 8;
    }
    const __hip_bfloat16* baseB = wt + (size_t)lm * 1728 + g * 8;

    const int KSB[5] = {0, 13, 27, 40, 54};
    int ks_b = KSB[w], ks_e = KSB[w + 1];

    f32x4 acc[2][4] = {};
    for (int ks = ks_b; ks < ks_e; ++ks) {
        int tap = ks / 6;                         // 6 k-steps per tap (192/32)
        int c0 = (ks - tap * 6) * 32;
        int aoff = ((tap / 3) * 98 + (tap % 3)) * 192 + c0;
        short8v a0 = *(const short8v*)(baseA[0] + aoff);
        short8v a1 = *(const short8v*)(baseA[1] + aoff);
        int boff = ks * 32;
        short8v b0 = *(const short8v*)(baseB + 0 * 16 * 1728 + boff);
        short8v b1 = *(const short8v*)(baseB + 1 * 16 * 1728 + boff);
        short8v b2 = *(const short8v*)(baseB + 2 * 16 * 1728 + boff);
        short8v b3 = *(const short8v*)(baseB + 3 * 16 * 1728 + boff);
        acc[0][0] = __builtin_amdgcn_mfma_f32_16x16x32_bf16(a0, b0, acc[0][0], 0, 0, 0);
        acc[0][1] = __builtin_amdgcn_mfma_f32_16x16x32_bf16(a0, b1, acc[0][1], 0, 0, 0);
        acc[0][2] = __builtin_amdgcn_mfma_f32_16x16x32_bf16(a0, b2, acc[0][2], 0, 0, 0);
        acc[0][3] = __builtin_amdgcn_mfma_f32_16x16x32_bf16(a0, b3, acc[0][3], 0, 0, 0);
        acc[1][0] = __builtin_amdgcn_mfma_f32_16x16x32_bf16(a1, b0, acc[1][0], 0, 0, 0);
        acc[1][1] = __builtin_amdgcn_mfma_f32_16x16x32_bf16(a1, b1, acc[1][1], 0, 0, 0);
        acc[1][2] = __builtin_amdgcn_mfma_f32_16x16x32_bf16(a1, b2, acc[1][2], 0, 0, 0);
        acc[1][3] = __builtin_amdgcn_mfma_f32_16x16x32_bf16(a1, b3, acc[1][3], 0, 0, 0);
    }

    #pragma unroll
    for (int mt = 0; mt < 2; ++mt)
        #pragma unroll
        for (int nt = 0; nt < 4; ++nt)
            red[((w * 2 + mt) * 4 + nt) * 64 + l] = acc[mt][nt];
    __syncthreads();

    #pragma unroll
    for (int i = 0; i < 8; ++i) {
        int e = tid * 8 + i;
        int o = e >> 5, px = e & 31;
        int mt = px >> 4, gg = (px >> 2) & 3, r = px & 3;
        int lane = gg * 16 + (o & 15), nt = o >> 4;
        float s = b_fuse[o];
        #pragma unroll
        for (int ww = 0; ww < 4; ++ww)
            s += red[((ww * 2 + mt) * 4 + nt) * 64 + lane][r];
        out[(size_t)(b * 64 + o) * HW + rem0 + px] = s;
    }
}

extern "C" void kernel_launch(void* const* d_in, const int* in_sizes, int n_in,
                              void* d_out, int out_size, void* d_ws, size_t ws_size,
                              hipStream_t stream) {
    const float* past     = (const float*)d_in[0];
    const float* curr     = (const float*)d_in[1];
    const float* w_smooth = (const float*)d_in[2];
    const float* b_smooth = (const float*)d_in[3];
    const float* w_reduce = (const float*)d_in[4];
    const float* b_reduce = (const float*)d_in[5];
    const float* w_v0     = (const float*)d_in[6];
    const float* b_v0     = (const float*)d_in[7];
    const float* w_v1     = (const float*)d_in[8];
    const float* b_v1     = (const float*)d_in[9];
    const float* rpb0     = (const float*)d_in[10];
    const float* rpb1     = (const float*)d_in[11];
    const float* w_fuse   = (const float*)d_in[12];
    const float* b_fuse   = (const float*)d_in[13];
    float* out = (float*)d_out;

    const size_t NF = (size_t)NPIX * 64;
    char* p = (char*)d_ws;
    auto carve = [&](size_t bytes) { char* r = p; p += (bytes + 255) & ~(size_t)255; return r; };
    __hip_bfloat16* featp    = (__hip_bfloat16*)carve((size_t)2 * 98 * 98 * 192 * 2);
    __hip_bfloat16* curr_b   = (__hip_bfloat16*)carve(NF * 2);
    __hip_bfloat16* past_b   = (__hip_bfloat16*)carve(NF * 2);
    __hip_bfloat16* smooth_b = (__hip_bfloat16*)carve(NF * 2);
    __hip_bfloat16* past2_b  = (__hip_bfloat16*)carve(NF * 2);
    __hip_bfloat16* v0_b     = (__hip_bfloat16*)carve(NF * 2);
    __hip_bfloat16* v1_b     = (__hip_bfloat16*)carve(NF * 2);
    __hip_bfloat16* wt_fuse  = (__hip_bfloat16*)carve((size_t)64 * 1728 * 2);
    __hip_bfloat16* wr_b     = (__hip_bfloat16*)carve((size_t)64 * 128 * 2);
    __hip_bfloat16* wv0_b    = (__hip_bfloat16*)carve((size_t)64 * 64 * 2);
    __hip_bfloat16* wv1_b    = (__hip_bfloat16*)carve((size_t)64 * 64 * 2);

    zero_border_k<<<(2 * 98 * 98 + 255) / 256, 256, 0, stream>>>(featp);
    prep_k<<<432, 256, 0, stream>>>(w_fuse, w_reduce, w_v0, w_v1, wt_fuse, wr_b, wv0_b, wv1_b);

    dim3 tb(32, 8, 1), tg(HW / 32, 2, 4);
    transpose_cl_k<<<tg, tb, 0, stream>>>(past, curr, curr_b, featp, past_b);
    smooth_k<<<NPIX / 64, 512, 0, stream>>>(past_b, w_smooth, b_smooth, smooth_b);
    reduce_mfma_k<<<NPIX / 32, 256, 0, stream>>>(past_b, smooth_b, wr_b, b_reduce, past2_b);
    vv_mfma_k<<<NPIX / 32, 256, 0, stream>>>(past2_b, wv0_b, wv1_b, b_v0, b_v1, v0_b, v1_b);
    natten_mfma_k<3><<<NPIX / 16, 256, 0, stream>>>(curr_b, past2_b, v0_b, rpb0, featp, 64);
    natten_mfma_k<7><<<NPIX / 16, 256, 0, stream>>>(curr_b, past2_b, v1_b, rpb1, featp, 128);
    fuse_v3_k<<<NPIX / 32, 256, 0, stream>>>(featp, wt_fuse, b_fuse, out);
}